// Round 21
// baseline (7270.338 us; speedup 1.0000x reference)
//
#include <hip/hip_runtime.h>
#include <math.h>

// ---------------------------------------------------------------------------
// Hierarchical bi-GRU (char bi-GRU -> word bi-GRU -> FC head).
//
// r21 = r19/r20 resubmitted verbatim (both benches died on the same broken
// broker pod before our code ever ran): r15 (best, 3628us) with the word
// persistent kernel re-shaped:
//   * weights pre-PACKED per-thread: WPg[t][k][2], WPc[t][k][1] (bf16) so
//     each thread's k-stream is contiguous -> 16B ushort8 loads
//   * 512 threads/block (8 waves = 2/SIMD, 2x stall overlap vs r12's 4)
//     WITHOUT the load-width loss that sank r11 (packing preserves 16B/lane)
//   * vmem instructions per step-thread: 1024 -> ~192 (5x fewer)
//   * same k-ascending fp32 accumulation -> bitwise-identical to r15
// Char level (MFMA GEMM loop) and stages A/C/D: r15 verbatim.
//
//   gates = sigmoid(x@Wg_x + h@Wg_h + bg)      (x-part precomputed)
//   c     = tanh  (x@Wc_x + (r*h)@Wc_h + bc)
//   h'    = mask ? u*h + (1-u)*c : h
// ---------------------------------------------------------------------------

#define TILE 64
#define BKK 16

typedef __attribute__((ext_vector_type(8))) short bshort8;
typedef __attribute__((ext_vector_type(4))) float f32x4;

enum AMode { A_PLAIN = 0, A_CHARSTATE = 1, A_RH = 2, A_GATHER = 3 };
enum EMode { E_BIAS = 0, E_GATE_CHAR = 1, E_CAND_CHAR = 2, E_XW = 3 };

struct GemmArgs {
  int M, N, K;
  const float* A; int lda;
  const float* G; int ldg;
  const int*   arows;
  const float* B;
  const float* bias;
  const float* XT; int ldxt;
  const int*   seqs;
  const int*   lens;
  int t, T;
  const int*   cidx;
  const float* Hin;
  float* Cout; int ldc;
};

__device__ __forceinline__ float sigmoidf_(float x) { return 1.0f / (1.0f + expf(-x)); }
__device__ __forceinline__ float bf2f_(unsigned short u) {
  return __uint_as_float((unsigned int)u << 16);
}
__device__ __forceinline__ unsigned short f2bf_(float f) {
  const unsigned int u = __float_as_uint(f);
  return (unsigned short)((u + 0x7FFFu + ((u >> 16) & 1u)) >> 16);
}

// --------------------------- fp32 64x64 tile GEMM (stages A, C, D) ----------
template<int AM, int EM>
__global__ __launch_bounds__(256) void gemm_k(GemmArgs p) {
  __shared__ float As[BKK][TILE];
  __shared__ float Bs[BKK][TILE];
  const int tid = threadIdx.x;
  const int tx = tid & 15, ty = tid >> 4;
  const int m0 = blockIdx.y * TILE, n0 = blockIdx.x * TILE;
  const int la_r = tid >> 2, la_k = (tid & 3) << 2;
  const int lb_k = tid >> 4, lb_n = (tid & 15) << 2;

  float acc[4][4] = {};
  int arow = 0;
  if constexpr (AM == A_GATHER) arow = p.arows[m0 + la_r];

  for (int k0 = 0; k0 < p.K; k0 += BKK) {
    float4 av;
    const int m = m0 + la_r;
    const int k = k0 + la_k;
    if constexpr (AM == A_PLAIN) {
      av = *reinterpret_cast<const float4*>(p.A + (size_t)m * p.lda + k);
    } else if constexpr (AM == A_CHARSTATE) {
      const float* ap = (k < 512) ? (p.A + (size_t)m * 512 + k)
                                  : (p.A + (size_t)(2048 + m) * 512 + (k - 512));
      av = *reinterpret_cast<const float4*>(ap);
    } else { // A_GATHER
      av = *reinterpret_cast<const float4*>(p.A + (size_t)arow * p.lda + k);
    }
    As[la_k + 0][la_r] = av.x;
    As[la_k + 1][la_r] = av.y;
    As[la_k + 2][la_r] = av.z;
    As[la_k + 3][la_r] = av.w;
    float4 bv = *reinterpret_cast<const float4*>(p.B + (size_t)(k0 + lb_k) * p.N + n0 + lb_n);
    *reinterpret_cast<float4*>(&Bs[lb_k][lb_n]) = bv;
    __syncthreads();
#pragma unroll
    for (int kk = 0; kk < BKK; ++kk) {
      float4 a = *reinterpret_cast<const float4*>(&As[kk][ty << 2]);
      float4 b = *reinterpret_cast<const float4*>(&Bs[kk][tx << 2]);
      acc[0][0] += a.x * b.x; acc[0][1] += a.x * b.y; acc[0][2] += a.x * b.z; acc[0][3] += a.x * b.w;
      acc[1][0] += a.y * b.x; acc[1][1] += a.y * b.y; acc[1][2] += a.y * b.z; acc[1][3] += a.y * b.w;
      acc[2][0] += a.z * b.x; acc[2][1] += a.z * b.y; acc[2][2] += a.z * b.z; acc[2][3] += a.z * b.w;
      acc[3][0] += a.w * b.x; acc[3][1] += a.w * b.y; acc[3][2] += a.w * b.z; acc[3][3] += a.w * b.w;
    }
    __syncthreads();
  }

  const int rbase = m0 + (ty << 2);
  const int cbase = n0 + (tx << 2);
#pragma unroll
  for (int i = 0; i < 4; ++i) {
    const int row = rbase + i;
    if constexpr (EM == E_BIAS) {
#pragma unroll
      for (int j = 0; j < 4; ++j) {
        const int col = cbase + j;
        p.Cout[(size_t)row * p.ldc + col] = acc[i][j] + p.bias[col];
      }
    } else { // E_XW
      const int cs = p.cidx[row];
      const float* xrow = p.XT + (size_t)cs * p.ldxt;
#pragma unroll
      for (int j = 0; j < 4; ++j) {
        const int col = cbase + j;
        p.Cout[(size_t)row * p.ldc + col] = acc[i][j] + xrow[col];
      }
    }
  }
}

// fp32 -> bf16 (RNE) weight conversion (char weights, row-major kept)
__global__ __launch_bounds__(256) void wconv_k(const float* __restrict__ src,
                                               unsigned short* __restrict__ dst,
                                               int n) {
  const int i = blockIdx.x * 256 + threadIdx.x;
  if (i < n) dst[i] = f2bf_(src[i]);
}

// fp32 -> bf16 pack for word weights: dst[t][k][CPT] = src[k][t*CPT + j]
// (per-thread contiguous k-streams; ldb = NT*CPT, K=512 rows)
template<int CPT>
__global__ __launch_bounds__(256) void wpack_k(const float* __restrict__ src,
                                               unsigned short* __restrict__ dst,
                                               int ldb) {
  const int i = blockIdx.x * 256 + threadIdx.x;
  const int n = 512 * ldb;
  if (i < n) {
    const int t = i / (512 * CPT);
    const int rem = i - t * (512 * CPT);
    const int k = rem / CPT;
    const int j = rem - k * CPT;
    dst[i] = f2bf_(src[(size_t)k * ldb + t * CPT + j]);
  }
}

// ---------------------------------------------------------------------------
// Char recurrent GEMM via bf16 MFMA (r15, proven). BM=64, BN (gate 128 /
// cand 64), BK=32, 256 threads = 4 waves. Fragment maps m89-verified.
// ---------------------------------------------------------------------------
template<int BN, int EM>
__global__ __launch_bounds__(256) void cgemm_mfma(
    const float* __restrict__ Ain,        // hcur [4096][512]
    const float* __restrict__ G,          // EM=1: Gc [4096][1024]
    const unsigned short* __restrict__ Bw,// bf16 weights [512][ldb]
    int ldb,
    const float* __restrict__ XT,         // x-part table (256 rows)
    const int* __restrict__ seqs,         // [2048][16]
    const int* __restrict__ lens,         // [2048]
    int t,
    const float* __restrict__ Hin,        // EM=1: hcur
    float* __restrict__ Cout, int ldc) {
  __shared__ unsigned short As[64][40];
  __shared__ unsigned short Bs[BN][40];
  __shared__ int xo_s[64];
  __shared__ int msk_s[64];

  const int tid = threadIdx.x;
  const int m0 = blockIdx.y * 64;
  const int n0 = blockIdx.x * BN;

  if (tid < 64) {
    const int grow = m0 + tid;
    const int us = grow & 2047;
    const bool dir = grow >= 2048;
    const int len = lens[us];
    int pos = dir ? (len - 1 - t) : t;
    pos = pos < 0 ? 0 : (pos > 15 ? 15 : pos);
    const int ch = seqs[us * 16 + pos];
    xo_s[tid] = ch * ((EM == 0) ? 1024 : 512);
    msk_s[tid] = (t < len) ? 1 : 0;
  }

  const int wid = tid >> 6, lane = tid & 63;
  const int lr = lane & 15, lk = (lane >> 4) << 3;
  constexpr int NI = BN / 64;
  const int c0w = wid * (BN / 4);

  f32x4 acc[4][NI];
#pragma unroll
  for (int mi = 0; mi < 4; ++mi)
#pragma unroll
    for (int ni = 0; ni < NI; ++ni) acc[mi][ni] = (f32x4){0.f, 0.f, 0.f, 0.f};

  const int arow = tid >> 2;
  const int akoff = (tid & 3) << 3;

  for (int k0 = 0; k0 < 512; k0 += 32) {
    {
      const float* ap = Ain + (size_t)(m0 + arow) * 512 + k0 + akoff;
      float4 a0 = *reinterpret_cast<const float4*>(ap);
      float4 a1 = *reinterpret_cast<const float4*>(ap + 4);
      if constexpr (EM == 1) {
        const float* gp = G + (size_t)(m0 + arow) * 1024 + k0 + akoff;
        float4 g0 = *reinterpret_cast<const float4*>(gp);
        float4 g1 = *reinterpret_cast<const float4*>(gp + 4);
        a0.x *= g0.x; a0.y *= g0.y; a0.z *= g0.z; a0.w *= g0.w;
        a1.x *= g1.x; a1.y *= g1.y; a1.z *= g1.z; a1.w *= g1.w;
      }
      bshort8 av;
      av[0] = (short)f2bf_(a0.x); av[1] = (short)f2bf_(a0.y);
      av[2] = (short)f2bf_(a0.z); av[3] = (short)f2bf_(a0.w);
      av[4] = (short)f2bf_(a1.x); av[5] = (short)f2bf_(a1.y);
      av[6] = (short)f2bf_(a1.z); av[7] = (short)f2bf_(a1.w);
      *reinterpret_cast<bshort8*>(&As[arow][akoff]) = av;
    }
    if (BN == 128 || tid < 128) {
      const int bc0 = (BN == 128) ? ((tid & 31) << 2) : ((tid & 15) << 2);
      const int bk0 = (BN == 128) ? ((tid >> 5) << 2) : ((tid >> 4) << 2);
      ushort4 b0 = *reinterpret_cast<const ushort4*>(Bw + (size_t)(k0 + bk0 + 0) * ldb + n0 + bc0);
      ushort4 b1 = *reinterpret_cast<const ushort4*>(Bw + (size_t)(k0 + bk0 + 1) * ldb + n0 + bc0);
      ushort4 b2 = *reinterpret_cast<const ushort4*>(Bw + (size_t)(k0 + bk0 + 2) * ldb + n0 + bc0);
      ushort4 b3 = *reinterpret_cast<const ushort4*>(Bw + (size_t)(k0 + bk0 + 3) * ldb + n0 + bc0);
      ushort4 w;
      w.x = b0.x; w.y = b1.x; w.z = b2.x; w.w = b3.x;
      *reinterpret_cast<ushort4*>(&Bs[bc0 + 0][bk0]) = w;
      w.x = b0.y; w.y = b1.y; w.z = b2.y; w.w = b3.y;
      *reinterpret_cast<ushort4*>(&Bs[bc0 + 1][bk0]) = w;
      w.x = b0.z; w.y = b1.z; w.z = b2.z; w.w = b3.z;
      *reinterpret_cast<ushort4*>(&Bs[bc0 + 2][bk0]) = w;
      w.x = b0.w; w.y = b1.w; w.z = b2.w; w.w = b3.w;
      *reinterpret_cast<ushort4*>(&Bs[bc0 + 3][bk0]) = w;
    }
    __syncthreads();

    bshort8 af[4];
#pragma unroll
    for (int mi = 0; mi < 4; ++mi)
      af[mi] = *reinterpret_cast<const bshort8*>(&As[mi * 16 + lr][lk]);
#pragma unroll
    for (int ni = 0; ni < NI; ++ni) {
      const bshort8 bf = *reinterpret_cast<const bshort8*>(&Bs[c0w + ni * 16 + lr][lk]);
#pragma unroll
      for (int mi = 0; mi < 4; ++mi)
        acc[mi][ni] = __builtin_amdgcn_mfma_f32_16x16x32_bf16(af[mi], bf, acc[mi][ni], 0, 0, 0);
    }
    __syncthreads();
  }

  const int rq = lane >> 4;
#pragma unroll
  for (int mi = 0; mi < 4; ++mi) {
#pragma unroll
    for (int ni = 0; ni < NI; ++ni) {
#pragma unroll
      for (int reg = 0; reg < 4; ++reg) {
        const int lrow = mi * 16 + rq * 4 + reg;
        const int grow = m0 + lrow;
        const int col = n0 + c0w + ni * 16 + lr;
        const float v = acc[mi][ni][reg];
        if constexpr (EM == 0) {
          Cout[(size_t)grow * ldc + col] = sigmoidf_(v + XT[xo_s[lrow] + col]);
        } else {
          const float cv = tanhf(v + XT[xo_s[lrow] + col]);
          const float u = G[(size_t)grow * 1024 + 512 + col];
          const float h = Hin[(size_t)grow * 512 + col];
          Cout[(size_t)grow * ldc + col] = msk_s[lrow] ? (u * h + (1.0f - u) * cv) : h;
        }
      }
    }
  }
}

// ---------------------------------------------------------------------------
// Fused persistent word GRU, PACKED bf16 weights, 512 threads (8 waves):
// phase 1: thread owns gate cols {2t,2t+1}; WPg[t][k][2] -> ushort8 = 4k.
// phase 2: thread owns cand col {t};        WPc[t][k][1] -> ushort8 = 8k.
// R=2 rows/block, 256 blocks. k-ascending fp32 accumulation (== r15 output).
// ---------------------------------------------------------------------------
template<int R, int NU, int TT>
__global__ __launch_bounds__(512) void gru_word_bf(
    const unsigned short* __restrict__ WPg,  // packed [512t][512k][2]
    const unsigned short* __restrict__ WPc,  // packed [512t][512k][1]
    const float* __restrict__ Xg,            // [NU*TT,1024] (bias folded)
    const float* __restrict__ Xc,            // [NU*TT,512]
    const int*   __restrict__ lens,          // [NU]
    float* __restrict__ Hout)                // [2*NU, 512]
{
  __shared__ float h_s [R][512];
  __shared__ float rh_s[R][512];
  __shared__ float u_s [R][512];
  __shared__ int   xog_s[R];
  __shared__ int   xoc_s[R];
  __shared__ int   msk_s[R];

  const int tid  = threadIdx.x;
  const int row0 = blockIdx.x * R;
  const int us0  = row0 & (NU - 1);
  const bool bw  = row0 >= NU;

  for (int i = tid; i < R * 512; i += 512) h_s[i >> 9][i & 511] = 0.0f;
  int mylen = 0;
  if (tid < R) mylen = lens[us0 + tid];
  __syncthreads();

  const int cg = tid << 1;   // phase-1 gate col pair [0,1024)
  const int cc = tid;        // phase-2 cand col [0,512)
  const unsigned short* wpg = WPg + (size_t)tid * 1024;  // 512k x 2 cols
  const unsigned short* wpc = WPc + (size_t)tid * 512;   // 512k x 1 col

  for (int t = 0; t < TT; ++t) {
    if (tid < R) {
      int pos = bw ? (mylen - 1 - t) : t;
      pos = pos < 0 ? 0 : (pos > TT - 1 ? TT - 1 : pos);
      const int xr = (us0 + tid) * TT + pos;
      xog_s[tid] = xr * 1024;
      xoc_s[tid] = xr * 512;
      msk_s[tid] = (t < mylen) ? 1 : 0;
    }
    __syncthreads();

    // ---- phase 1: gates = sigmoid(h @ Whg + Xg); rh / u -> LDS ----
    float2 acc[R];
#pragma unroll
    for (int r = 0; r < R; ++r) acc[r] = make_float2(0.f, 0.f);
#pragma unroll 4
    for (int k0 = 0; k0 < 512; k0 += 4) {
      const bshort8 w = *reinterpret_cast<const bshort8*>(wpg + k0 * 2);
      float4 hv[R];
#pragma unroll
      for (int r = 0; r < R; ++r)
        hv[r] = *reinterpret_cast<const float4*>(&h_s[r][k0]);
#pragma unroll
      for (int i = 0; i < 4; ++i) {
        const float wx = bf2f_((unsigned short)w[2 * i]);
        const float wy = bf2f_((unsigned short)w[2 * i + 1]);
#pragma unroll
        for (int r = 0; r < R; ++r) {
          const float hval = (i == 0) ? hv[r].x : (i == 1) ? hv[r].y : (i == 2) ? hv[r].z : hv[r].w;
          acc[r].x += hval * wx; acc[r].y += hval * wy;
        }
      }
    }
#pragma unroll
    for (int r = 0; r < R; ++r) {
      const float2 x = *reinterpret_cast<const float2*>(Xg + xog_s[r] + cg);
      float2 g;
      g.x = sigmoidf_(acc[r].x + x.x);
      g.y = sigmoidf_(acc[r].y + x.y);
      if (cg < 512) {        // r-gate cols -> rh = r * h
        rh_s[r][cg + 0] = g.x * h_s[r][cg + 0];
        rh_s[r][cg + 1] = g.y * h_s[r][cg + 1];
      } else {               // u-gate cols
        u_s[r][cg - 512 + 0] = g.x;
        u_s[r][cg - 512 + 1] = g.y;
      }
    }
    __syncthreads();

    // ---- phase 2: c = tanh(rh @ Whc + Xc); h' = mask ? u*h+(1-u)*c : h ----
    float acc2[R];
#pragma unroll
    for (int r = 0; r < R; ++r) acc2[r] = 0.f;
#pragma unroll 4
    for (int k0 = 0; k0 < 512; k0 += 8) {
      const bshort8 w = *reinterpret_cast<const bshort8*>(wpc + k0);
      float4 r0[R], r1[R];
#pragma unroll
      for (int r = 0; r < R; ++r) {
        r0[r] = *reinterpret_cast<const float4*>(&rh_s[r][k0]);
        r1[r] = *reinterpret_cast<const float4*>(&rh_s[r][k0 + 4]);
      }
#pragma unroll
      for (int i = 0; i < 8; ++i) {
        const float wv = bf2f_((unsigned short)w[i]);
#pragma unroll
        for (int r = 0; r < R; ++r) {
          const float rv = (i == 0) ? r0[r].x : (i == 1) ? r0[r].y : (i == 2) ? r0[r].z :
                           (i == 3) ? r0[r].w : (i == 4) ? r1[r].x : (i == 5) ? r1[r].y :
                           (i == 6) ? r1[r].z : r1[r].w;
          acc2[r] += rv * wv;
        }
      }
    }
#pragma unroll
    for (int r = 0; r < R; ++r) {
      const float cv = tanhf(acc2[r] + Xc[xoc_s[r] + cc]);
      if (msk_s[r]) {
        const float u = u_s[r][cc];
        const float h = h_s[r][cc];
        h_s[r][cc] = u * h + (1.0f - u) * cv;
      }
    }
    __syncthreads();
  }

  for (int i = tid; i < R * 512; i += 512)
    Hout[(size_t)(row0 + (i >> 9)) * 512 + (i & 511)] = h_s[i >> 9][i & 511];
}

// FC head
__global__ __launch_bounds__(64) void head_k(const float* __restrict__ Hw,
                                             const float* __restrict__ W1,
                                             const float* __restrict__ b1,
                                             const float* __restrict__ W2,
                                             const float* __restrict__ b2,
                                             float* __restrict__ out) {
  __shared__ float s[1024];
  __shared__ float hid[64];
  const int b = blockIdx.x;
  const int tid = threadIdx.x;
  for (int k = tid; k < 512; k += 64) {
    s[k]       = Hw[(size_t)b * 512 + k];
    s[512 + k] = Hw[(size_t)(256 + b) * 512 + k];
  }
  __syncthreads();
  float acc = b1[tid];
  for (int k = 0; k < 1024; ++k) acc += s[k] * W1[k * 64 + tid];
  acc = acc > 0.0f ? acc : 0.2f * acc;
  hid[tid] = acc;
  __syncthreads();
  if (tid < 2) {
    float a = b2[tid];
    for (int k = 0; k < 64; ++k) a += hid[k] * W2[k * 2 + tid];
    out[b * 2 + tid] = a;
  }
}

extern "C" void kernel_launch(void* const* d_in, const int* in_sizes, int n_in,
                              void* d_out, int out_size, void* d_ws, size_t ws_size,
                              hipStream_t stream) {
  const int*   charseqs      = (const int*)d_in[0];
  const int*   charseq_lens  = (const int*)d_in[1];
  const int*   charseq_ids   = (const int*)d_in[2];
  const int*   word_ids      = (const int*)d_in[3];
  const int*   sentence_lens = (const int*)d_in[4];
  const float* char_emb      = (const float*)d_in[5];
  const float* word_emb      = (const float*)d_in[6];
  const float* Wg_c          = (const float*)d_in[7];
  const float* bg_c          = (const float*)d_in[8];
  const float* Wc_c          = (const float*)d_in[9];
  const float* bc_c          = (const float*)d_in[10];
  const float* Wg_w          = (const float*)d_in[11];
  const float* bg_w          = (const float*)d_in[12];
  const float* Wc_w          = (const float*)d_in[13];
  const float* bc_w          = (const float*)d_in[14];
  const float* W1            = (const float*)d_in[15];
  const float* b1            = (const float*)d_in[16];
  const float* W2            = (const float*)d_in[17];
  const float* b2            = (const float*)d_in[18];
  float* out = (float*)d_out;

  float* ws = (float*)d_ws;
  size_t off = 0;
  auto alloc = [&](size_t n) { float* p = ws + off; off += n; return p; };
  float* XTABg = alloc(256 * 1024);
  float* XTABc = alloc(256 * 512);
  float* HcA   = alloc((size_t)4096 * 512);
  float* HcB   = alloc((size_t)4096 * 512);
  float* Gc    = alloc((size_t)4096 * 1024);
  float* CTABg = alloc((size_t)2048 * 1024);
  float* CTABc = alloc((size_t)2048 * 512);
  float* XWg   = alloc((size_t)16384 * 1024);
  float* XWc   = alloc((size_t)16384 * 512);
  float* Hw    = alloc(512 * 512);
  unsigned short* WPg   = (unsigned short*)alloc(512 * 1024 / 2); // word gate, packed
  unsigned short* WPc   = (unsigned short*)alloc(512 * 512 / 2);  // word cand, packed
  unsigned short* WgcBF = (unsigned short*)alloc(512 * 1024 / 2); // char gate
  unsigned short* WccBF = (unsigned short*)alloc(512 * 512 / 2);  // char cand

  hipMemsetAsync(HcA, 0, (size_t)4096 * 512 * sizeof(float), stream);

  // --- Stage 0: weight conversions (char row-major bf16; word packed bf16) ---
  wpack_k<2><<<(512 * 1024 + 255) / 256, 256, 0, stream>>>(
      Wg_w + (size_t)1280 * 1024, WPg, 1024);
  wpack_k<1><<<(512 * 512 + 255) / 256, 256, 0, stream>>>(
      Wc_w + (size_t)1280 * 512, WPc, 512);
  wconv_k<<<(512 * 1024 + 255) / 256, 256, 0, stream>>>(
      Wg_c + 128 * 1024, WgcBF, 512 * 1024);
  wconv_k<<<(512 * 512 + 255) / 256, 256, 0, stream>>>(
      Wc_c + 128 * 512, WccBF, 512 * 512);

  // --- Stage A: char x-part tables (fp32) ---
  {
    GemmArgs a{}; a.M = 256; a.N = 1024; a.K = 128;
    a.A = char_emb; a.lda = 128; a.B = Wg_c; a.bias = bg_c; a.Cout = XTABg; a.ldc = 1024;
    gemm_k<A_PLAIN, E_BIAS><<<dim3(1024 / TILE, 256 / TILE), 256, 0, stream>>>(a);
    GemmArgs c{}; c.M = 256; c.N = 512; c.K = 128;
    c.A = char_emb; c.lda = 128; c.B = Wc_c; c.bias = bc_c; c.Cout = XTABc; c.ldc = 512;
    gemm_k<A_PLAIN, E_BIAS><<<dim3(512 / TILE, 256 / TILE), 256, 0, stream>>>(c);
  }

  // --- Stage B: char bi-GRU, MFMA bf16 GEMM loop (r15, proven) ---
  float* hcur = HcA; float* hnext = HcB;
  for (int t = 0; t < 16; ++t) {
    cgemm_mfma<128, 0><<<dim3(1024 / 128, 4096 / 64), 256, 0, stream>>>(
        hcur, nullptr, WgcBF, 1024, XTABg, charseqs, charseq_lens, t, nullptr,
        Gc, 1024);
    cgemm_mfma<64, 1><<<dim3(512 / 64, 4096 / 64), 256, 0, stream>>>(
        hcur, Gc, WccBF, 512, XTABc, charseqs, charseq_lens, t, hcur,
        hnext, 512);
    float* tmp = hcur; hcur = hnext; hnext = tmp;
  }
  // after 16 steps hcur == HcA

  // --- Stage C: per-wordform x-part (fp32) ---
  {
    GemmArgs a{}; a.M = 2048; a.N = 1024; a.K = 1024;
    a.A = hcur; a.B = Wg_w; a.bias = bg_w; a.Cout = CTABg; a.ldc = 1024;
    gemm_k<A_CHARSTATE, E_BIAS><<<dim3(1024 / TILE, 2048 / TILE), 256, 0, stream>>>(a);
    GemmArgs c{}; c.M = 2048; c.N = 512; c.K = 1024;
    c.A = hcur; c.B = Wc_w; c.bias = bc_w; c.Cout = CTABc; c.ldc = 512;
    gemm_k<A_CHARSTATE, E_BIAS><<<dim3(512 / TILE, 2048 / TILE), 256, 0, stream>>>(c);
  }

  // --- Stage D: word-emb x-part + CTAB gather (fp32) ---
  {
    GemmArgs a{}; a.M = 16384; a.N = 1024; a.K = 256;
    a.A = word_emb; a.lda = 256; a.arows = word_ids; a.B = Wg_w + (size_t)1024 * 1024;
    a.XT = CTABg; a.ldxt = 1024; a.cidx = charseq_ids; a.Cout = XWg; a.ldc = 1024;
    gemm_k<A_GATHER, E_XW><<<dim3(1024 / TILE, 16384 / TILE), 256, 0, stream>>>(a);
    GemmArgs c{}; c.M = 16384; c.N = 512; c.K = 256;
    c.A = word_emb; c.lda = 256; c.arows = word_ids; c.B = Wc_w + (size_t)1024 * 512;
    c.XT = CTABc; c.ldxt = 512; c.cidx = charseq_ids; c.Cout = XWc; c.ldc = 512;
    gemm_k<A_GATHER, E_XW><<<dim3(512 / TILE, 16384 / TILE), 256, 0, stream>>>(c);
  }

  // --- Stage E: fused word bi-GRU, packed bf16 weights (R=2, 256 x 512thr) ---
  gru_word_bf<2, 256, 64><<<256, 512, 0, stream>>>(
      WPg, WPc, XWg, XWc, sentence_lens, Hw);

  // --- Stage F: FC head ---
  head_k<<<256, 64, 0, stream>>>(Hw, W1, b1, W2, b2, out);
}

// Round 22
// 3628.731 us; speedup vs baseline: 2.0035x; 2.0035x over previous
//
#include <hip/hip_runtime.h>
#include <math.h>

// ---------------------------------------------------------------------------
// Hierarchical bi-GRU (char bi-GRU -> word bi-GRU -> FC head).
//
// r22 = r15 VERBATIM (measured session best: 3628us, absmax 1.2e-4).
// Word level: persistent bf16-VALU kernel, R=2, 256 blocks x 256 threads,
// row-major weights (wave-coalesced loads; r21 proved per-thread packing
// destroys coalescing: 2430 -> 6260us). Char level: bf16 MFMA GEMM loop.
// Stages A/C/D: fp32 64x64-tile GEMMs.
//
//   gates = sigmoid(x@Wg_x + h@Wg_h + bg)      (x-part precomputed)
//   c     = tanh  (x@Wc_x + (r*h)@Wc_h + bc)
//   h'    = mask ? u*h + (1-u)*c : h
// ---------------------------------------------------------------------------

#define TILE 64
#define BKK 16

typedef __attribute__((ext_vector_type(8))) short bshort8;
typedef __attribute__((ext_vector_type(4))) float f32x4;

enum AMode { A_PLAIN = 0, A_CHARSTATE = 1, A_RH = 2, A_GATHER = 3 };
enum EMode { E_BIAS = 0, E_GATE_CHAR = 1, E_CAND_CHAR = 2, E_XW = 3 };

struct GemmArgs {
  int M, N, K;
  const float* A; int lda;
  const float* G; int ldg;
  const int*   arows;
  const float* B;
  const float* bias;
  const float* XT; int ldxt;
  const int*   seqs;
  const int*   lens;
  int t, T;
  const int*   cidx;
  const float* Hin;
  float* Cout; int ldc;
};

__device__ __forceinline__ float sigmoidf_(float x) { return 1.0f / (1.0f + expf(-x)); }
__device__ __forceinline__ float bf2f_(unsigned short u) {
  return __uint_as_float((unsigned int)u << 16);
}
__device__ __forceinline__ unsigned short f2bf_(float f) {
  const unsigned int u = __float_as_uint(f);
  return (unsigned short)((u + 0x7FFFu + ((u >> 16) & 1u)) >> 16);
}

// --------------------------- fp32 64x64 tile GEMM (stages A, C, D) ----------
template<int AM, int EM>
__global__ __launch_bounds__(256) void gemm_k(GemmArgs p) {
  __shared__ float As[BKK][TILE];
  __shared__ float Bs[BKK][TILE];
  const int tid = threadIdx.x;
  const int tx = tid & 15, ty = tid >> 4;
  const int m0 = blockIdx.y * TILE, n0 = blockIdx.x * TILE;
  const int la_r = tid >> 2, la_k = (tid & 3) << 2;
  const int lb_k = tid >> 4, lb_n = (tid & 15) << 2;

  float acc[4][4] = {};
  int arow = 0;
  if constexpr (AM == A_GATHER) arow = p.arows[m0 + la_r];

  for (int k0 = 0; k0 < p.K; k0 += BKK) {
    float4 av;
    const int m = m0 + la_r;
    const int k = k0 + la_k;
    if constexpr (AM == A_PLAIN) {
      av = *reinterpret_cast<const float4*>(p.A + (size_t)m * p.lda + k);
    } else if constexpr (AM == A_CHARSTATE) {
      const float* ap = (k < 512) ? (p.A + (size_t)m * 512 + k)
                                  : (p.A + (size_t)(2048 + m) * 512 + (k - 512));
      av = *reinterpret_cast<const float4*>(ap);
    } else { // A_GATHER
      av = *reinterpret_cast<const float4*>(p.A + (size_t)arow * p.lda + k);
    }
    As[la_k + 0][la_r] = av.x;
    As[la_k + 1][la_r] = av.y;
    As[la_k + 2][la_r] = av.z;
    As[la_k + 3][la_r] = av.w;
    float4 bv = *reinterpret_cast<const float4*>(p.B + (size_t)(k0 + lb_k) * p.N + n0 + lb_n);
    *reinterpret_cast<float4*>(&Bs[lb_k][lb_n]) = bv;
    __syncthreads();
#pragma unroll
    for (int kk = 0; kk < BKK; ++kk) {
      float4 a = *reinterpret_cast<const float4*>(&As[kk][ty << 2]);
      float4 b = *reinterpret_cast<const float4*>(&Bs[kk][tx << 2]);
      acc[0][0] += a.x * b.x; acc[0][1] += a.x * b.y; acc[0][2] += a.x * b.z; acc[0][3] += a.x * b.w;
      acc[1][0] += a.y * b.x; acc[1][1] += a.y * b.y; acc[1][2] += a.y * b.z; acc[1][3] += a.y * b.w;
      acc[2][0] += a.z * b.x; acc[2][1] += a.z * b.y; acc[2][2] += a.z * b.z; acc[2][3] += a.z * b.w;
      acc[3][0] += a.w * b.x; acc[3][1] += a.w * b.y; acc[3][2] += a.w * b.z; acc[3][3] += a.w * b.w;
    }
    __syncthreads();
  }

  const int rbase = m0 + (ty << 2);
  const int cbase = n0 + (tx << 2);
#pragma unroll
  for (int i = 0; i < 4; ++i) {
    const int row = rbase + i;
    if constexpr (EM == E_BIAS) {
#pragma unroll
      for (int j = 0; j < 4; ++j) {
        const int col = cbase + j;
        p.Cout[(size_t)row * p.ldc + col] = acc[i][j] + p.bias[col];
      }
    } else { // E_XW
      const int cs = p.cidx[row];
      const float* xrow = p.XT + (size_t)cs * p.ldxt;
#pragma unroll
      for (int j = 0; j < 4; ++j) {
        const int col = cbase + j;
        p.Cout[(size_t)row * p.ldc + col] = acc[i][j] + xrow[col];
      }
    }
  }
}

// fp32 -> bf16 (RNE) weight conversion
__global__ __launch_bounds__(256) void wconv_k(const float* __restrict__ src,
                                               unsigned short* __restrict__ dst,
                                               int n) {
  const int i = blockIdx.x * 256 + threadIdx.x;
  if (i < n) dst[i] = f2bf_(src[i]);
}

// ---------------------------------------------------------------------------
// Char recurrent GEMM via bf16 MFMA. BM=64, BN (gate 128 / cand 64), BK=32,
// 256 threads = 4 waves. Fragment maps m89-verified.
// ---------------------------------------------------------------------------
template<int BN, int EM>
__global__ __launch_bounds__(256) void cgemm_mfma(
    const float* __restrict__ Ain,        // hcur [4096][512]
    const float* __restrict__ G,          // EM=1: Gc [4096][1024]
    const unsigned short* __restrict__ Bw,// bf16 weights [512][ldb]
    int ldb,
    const float* __restrict__ XT,         // x-part table (256 rows)
    const int* __restrict__ seqs,         // [2048][16]
    const int* __restrict__ lens,         // [2048]
    int t,
    const float* __restrict__ Hin,        // EM=1: hcur
    float* __restrict__ Cout, int ldc) {
  __shared__ unsigned short As[64][40];
  __shared__ unsigned short Bs[BN][40];
  __shared__ int xo_s[64];
  __shared__ int msk_s[64];

  const int tid = threadIdx.x;
  const int m0 = blockIdx.y * 64;
  const int n0 = blockIdx.x * BN;

  if (tid < 64) {
    const int grow = m0 + tid;
    const int us = grow & 2047;
    const bool dir = grow >= 2048;
    const int len = lens[us];
    int pos = dir ? (len - 1 - t) : t;
    pos = pos < 0 ? 0 : (pos > 15 ? 15 : pos);
    const int ch = seqs[us * 16 + pos];
    xo_s[tid] = ch * ((EM == 0) ? 1024 : 512);
    msk_s[tid] = (t < len) ? 1 : 0;
  }

  const int wid = tid >> 6, lane = tid & 63;
  const int lr = lane & 15, lk = (lane >> 4) << 3;
  constexpr int NI = BN / 64;
  const int c0w = wid * (BN / 4);

  f32x4 acc[4][NI];
#pragma unroll
  for (int mi = 0; mi < 4; ++mi)
#pragma unroll
    for (int ni = 0; ni < NI; ++ni) acc[mi][ni] = (f32x4){0.f, 0.f, 0.f, 0.f};

  const int arow = tid >> 2;
  const int akoff = (tid & 3) << 3;

  for (int k0 = 0; k0 < 512; k0 += 32) {
    {
      const float* ap = Ain + (size_t)(m0 + arow) * 512 + k0 + akoff;
      float4 a0 = *reinterpret_cast<const float4*>(ap);
      float4 a1 = *reinterpret_cast<const float4*>(ap + 4);
      if constexpr (EM == 1) {
        const float* gp = G + (size_t)(m0 + arow) * 1024 + k0 + akoff;
        float4 g0 = *reinterpret_cast<const float4*>(gp);
        float4 g1 = *reinterpret_cast<const float4*>(gp + 4);
        a0.x *= g0.x; a0.y *= g0.y; a0.z *= g0.z; a0.w *= g0.w;
        a1.x *= g1.x; a1.y *= g1.y; a1.z *= g1.z; a1.w *= g1.w;
      }
      bshort8 av;
      av[0] = (short)f2bf_(a0.x); av[1] = (short)f2bf_(a0.y);
      av[2] = (short)f2bf_(a0.z); av[3] = (short)f2bf_(a0.w);
      av[4] = (short)f2bf_(a1.x); av[5] = (short)f2bf_(a1.y);
      av[6] = (short)f2bf_(a1.z); av[7] = (short)f2bf_(a1.w);
      *reinterpret_cast<bshort8*>(&As[arow][akoff]) = av;
    }
    if (BN == 128 || tid < 128) {
      const int bc0 = (BN == 128) ? ((tid & 31) << 2) : ((tid & 15) << 2);
      const int bk0 = (BN == 128) ? ((tid >> 5) << 2) : ((tid >> 4) << 2);
      ushort4 b0 = *reinterpret_cast<const ushort4*>(Bw + (size_t)(k0 + bk0 + 0) * ldb + n0 + bc0);
      ushort4 b1 = *reinterpret_cast<const ushort4*>(Bw + (size_t)(k0 + bk0 + 1) * ldb + n0 + bc0);
      ushort4 b2 = *reinterpret_cast<const ushort4*>(Bw + (size_t)(k0 + bk0 + 2) * ldb + n0 + bc0);
      ushort4 b3 = *reinterpret_cast<const ushort4*>(Bw + (size_t)(k0 + bk0 + 3) * ldb + n0 + bc0);
      ushort4 w;
      w.x = b0.x; w.y = b1.x; w.z = b2.x; w.w = b3.x;
      *reinterpret_cast<ushort4*>(&Bs[bc0 + 0][bk0]) = w;
      w.x = b0.y; w.y = b1.y; w.z = b2.y; w.w = b3.y;
      *reinterpret_cast<ushort4*>(&Bs[bc0 + 1][bk0]) = w;
      w.x = b0.z; w.y = b1.z; w.z = b2.z; w.w = b3.z;
      *reinterpret_cast<ushort4*>(&Bs[bc0 + 2][bk0]) = w;
      w.x = b0.w; w.y = b1.w; w.z = b2.w; w.w = b3.w;
      *reinterpret_cast<ushort4*>(&Bs[bc0 + 3][bk0]) = w;
    }
    __syncthreads();

    bshort8 af[4];
#pragma unroll
    for (int mi = 0; mi < 4; ++mi)
      af[mi] = *reinterpret_cast<const bshort8*>(&As[mi * 16 + lr][lk]);
#pragma unroll
    for (int ni = 0; ni < NI; ++ni) {
      const bshort8 bf = *reinterpret_cast<const bshort8*>(&Bs[c0w + ni * 16 + lr][lk]);
#pragma unroll
      for (int mi = 0; mi < 4; ++mi)
        acc[mi][ni] = __builtin_amdgcn_mfma_f32_16x16x32_bf16(af[mi], bf, acc[mi][ni], 0, 0, 0);
    }
    __syncthreads();
  }

  const int rq = lane >> 4;
#pragma unroll
  for (int mi = 0; mi < 4; ++mi) {
#pragma unroll
    for (int ni = 0; ni < NI; ++ni) {
#pragma unroll
      for (int reg = 0; reg < 4; ++reg) {
        const int lrow = mi * 16 + rq * 4 + reg;
        const int grow = m0 + lrow;
        const int col = n0 + c0w + ni * 16 + lr;
        const float v = acc[mi][ni][reg];
        if constexpr (EM == 0) {
          Cout[(size_t)grow * ldc + col] = sigmoidf_(v + XT[xo_s[lrow] + col]);
        } else {
          const float cv = tanhf(v + XT[xo_s[lrow] + col]);
          const float u = G[(size_t)grow * 1024 + 512 + col];
          const float h = Hin[(size_t)grow * 512 + col];
          Cout[(size_t)grow * ldc + col] = msk_s[lrow] ? (u * h + (1.0f - u) * cv) : h;
        }
      }
    }
  }
}

// ---------------------------------------------------------------------------
// Fused persistent word GRU, bf16 weights (r12 config: R=2, 256 blocks x 256
// threads, row-major wave-coalesced weight loads).
// ---------------------------------------------------------------------------
template<int R, int NU, int TT>
__global__ __launch_bounds__(256) void gru_word_bf(
    const unsigned short* __restrict__ Whg,  // [512,1024] bf16
    const unsigned short* __restrict__ Whc,  // [512,512]  bf16
    const float* __restrict__ Xg,            // [NU*TT,1024] (bias folded)
    const float* __restrict__ Xc,            // [NU*TT,512]
    const int*   __restrict__ lens,          // [NU]
    float* __restrict__ Hout)                // [2*NU, 512]
{
  __shared__ float h_s [R][512];
  __shared__ float rh_s[R][512];
  __shared__ float u_s [R][512];
  __shared__ int   xog_s[R];
  __shared__ int   xoc_s[R];
  __shared__ int   msk_s[R];

  const int tid  = threadIdx.x;
  const int row0 = blockIdx.x * R;
  const int us0  = row0 & (NU - 1);
  const bool bw  = row0 >= NU;

  for (int i = tid; i < R * 512; i += 256) h_s[i >> 9][i & 511] = 0.0f;
  int mylen = 0;
  if (tid < R) mylen = lens[us0 + tid];
  __syncthreads();

  const int c0 = tid << 2;   // phase-1: 4 gate cols of 1024
  const int c2 = tid << 1;   // phase-2: 2 cand cols of 512

  for (int t = 0; t < TT; ++t) {
    if (tid < R) {
      int pos = bw ? (mylen - 1 - t) : t;
      pos = pos < 0 ? 0 : (pos > TT - 1 ? TT - 1 : pos);
      const int xr = (us0 + tid) * TT + pos;
      xog_s[tid] = xr * 1024;
      xoc_s[tid] = xr * 512;
      msk_s[tid] = (t < mylen) ? 1 : 0;
    }
    __syncthreads();

    // ---- phase 1: gates = sigmoid(h @ Whg + Xg); rh / u -> LDS ----
    float4 acc[R];
#pragma unroll
    for (int r = 0; r < R; ++r) acc[r] = make_float4(0.f, 0.f, 0.f, 0.f);
#pragma unroll 2
    for (int k0 = 0; k0 < 512; k0 += 4) {
      ushort4 wu[4];
#pragma unroll
      for (int i = 0; i < 4; ++i)
        wu[i] = *reinterpret_cast<const ushort4*>(Whg + (size_t)(k0 + i) * 1024 + c0);
      float4 hv[R];
#pragma unroll
      for (int r = 0; r < R; ++r)
        hv[r] = *reinterpret_cast<const float4*>(&h_s[r][k0]);
#pragma unroll
      for (int i = 0; i < 4; ++i) {
        const float wx = bf2f_(wu[i].x), wy = bf2f_(wu[i].y);
        const float wz = bf2f_(wu[i].z), ww = bf2f_(wu[i].w);
#pragma unroll
        for (int r = 0; r < R; ++r) {
          const float h = (i == 0) ? hv[r].x : (i == 1) ? hv[r].y : (i == 2) ? hv[r].z : hv[r].w;
          acc[r].x += h * wx; acc[r].y += h * wy;
          acc[r].z += h * wz; acc[r].w += h * ww;
        }
      }
    }
#pragma unroll
    for (int r = 0; r < R; ++r) {
      const float4 x = *reinterpret_cast<const float4*>(Xg + xog_s[r] + c0);
      float4 g;
      g.x = sigmoidf_(acc[r].x + x.x);
      g.y = sigmoidf_(acc[r].y + x.y);
      g.z = sigmoidf_(acc[r].z + x.z);
      g.w = sigmoidf_(acc[r].w + x.w);
      if (c0 < 512) {        // r-gate cols -> rh = r * h
        const float4 hh = *reinterpret_cast<const float4*>(&h_s[r][c0]);
        rh_s[r][c0 + 0] = g.x * hh.x;
        rh_s[r][c0 + 1] = g.y * hh.y;
        rh_s[r][c0 + 2] = g.z * hh.z;
        rh_s[r][c0 + 3] = g.w * hh.w;
      } else {               // u-gate cols
        u_s[r][c0 - 512 + 0] = g.x;
        u_s[r][c0 - 512 + 1] = g.y;
        u_s[r][c0 - 512 + 2] = g.z;
        u_s[r][c0 - 512 + 3] = g.w;
      }
    }
    __syncthreads();

    // ---- phase 2: c = tanh(rh @ Whc + Xc); h' = mask ? u*h+(1-u)*c : h ----
    float2 acc2[R];
#pragma unroll
    for (int r = 0; r < R; ++r) acc2[r] = make_float2(0.f, 0.f);
#pragma unroll 2
    for (int k0 = 0; k0 < 512; k0 += 4) {
      ushort2 wu[4];
#pragma unroll
      for (int i = 0; i < 4; ++i)
        wu[i] = *reinterpret_cast<const ushort2*>(Whc + (size_t)(k0 + i) * 512 + c2);
      float4 rv[R];
#pragma unroll
      for (int r = 0; r < R; ++r)
        rv[r] = *reinterpret_cast<const float4*>(&rh_s[r][k0]);
#pragma unroll
      for (int i = 0; i < 4; ++i) {
        const float wx = bf2f_(wu[i].x), wy = bf2f_(wu[i].y);
#pragma unroll
        for (int r = 0; r < R; ++r) {
          const float rvv = (i == 0) ? rv[r].x : (i == 1) ? rv[r].y : (i == 2) ? rv[r].z : rv[r].w;
          acc2[r].x += rvv * wx; acc2[r].y += rvv * wy;
        }
      }
    }
#pragma unroll
    for (int r = 0; r < R; ++r) {
      const float2 x = *reinterpret_cast<const float2*>(Xc + xoc_s[r] + c2);
      const float cx = tanhf(acc2[r].x + x.x);
      const float cy = tanhf(acc2[r].y + x.y);
      if (msk_s[r]) {
        const float ux = u_s[r][c2], uy = u_s[r][c2 + 1];
        const float hx = h_s[r][c2], hy = h_s[r][c2 + 1];
        h_s[r][c2]     = ux * hx + (1.0f - ux) * cx;
        h_s[r][c2 + 1] = uy * hy + (1.0f - uy) * cy;
      }
    }
    __syncthreads();
  }

  for (int i = tid; i < R * 512; i += 256)
    Hout[(size_t)(row0 + (i >> 9)) * 512 + (i & 511)] = h_s[i >> 9][i & 511];
}

// FC head
__global__ __launch_bounds__(64) void head_k(const float* __restrict__ Hw,
                                             const float* __restrict__ W1,
                                             const float* __restrict__ b1,
                                             const float* __restrict__ W2,
                                             const float* __restrict__ b2,
                                             float* __restrict__ out) {
  __shared__ float s[1024];
  __shared__ float hid[64];
  const int b = blockIdx.x;
  const int tid = threadIdx.x;
  for (int k = tid; k < 512; k += 64) {
    s[k]       = Hw[(size_t)b * 512 + k];
    s[512 + k] = Hw[(size_t)(256 + b) * 512 + k];
  }
  __syncthreads();
  float acc = b1[tid];
  for (int k = 0; k < 1024; ++k) acc += s[k] * W1[k * 64 + tid];
  acc = acc > 0.0f ? acc : 0.2f * acc;
  hid[tid] = acc;
  __syncthreads();
  if (tid < 2) {
    float a = b2[tid];
    for (int k = 0; k < 64; ++k) a += hid[k] * W2[k * 2 + tid];
    out[b * 2 + tid] = a;
  }
}

extern "C" void kernel_launch(void* const* d_in, const int* in_sizes, int n_in,
                              void* d_out, int out_size, void* d_ws, size_t ws_size,
                              hipStream_t stream) {
  const int*   charseqs      = (const int*)d_in[0];
  const int*   charseq_lens  = (const int*)d_in[1];
  const int*   charseq_ids   = (const int*)d_in[2];
  const int*   word_ids      = (const int*)d_in[3];
  const int*   sentence_lens = (const int*)d_in[4];
  const float* char_emb      = (const float*)d_in[5];
  const float* word_emb      = (const float*)d_in[6];
  const float* Wg_c          = (const float*)d_in[7];
  const float* bg_c          = (const float*)d_in[8];
  const float* Wc_c          = (const float*)d_in[9];
  const float* bc_c          = (const float*)d_in[10];
  const float* Wg_w          = (const float*)d_in[11];
  const float* bg_w          = (const float*)d_in[12];
  const float* Wc_w          = (const float*)d_in[13];
  const float* bc_w          = (const float*)d_in[14];
  const float* W1            = (const float*)d_in[15];
  const float* b1            = (const float*)d_in[16];
  const float* W2            = (const float*)d_in[17];
  const float* b2            = (const float*)d_in[18];
  float* out = (float*)d_out;

  float* ws = (float*)d_ws;
  size_t off = 0;
  auto alloc = [&](size_t n) { float* p = ws + off; off += n; return p; };
  float* XTABg = alloc(256 * 1024);
  float* XTABc = alloc(256 * 512);
  float* HcA   = alloc((size_t)4096 * 512);
  float* HcB   = alloc((size_t)4096 * 512);
  float* Gc    = alloc((size_t)4096 * 1024);
  float* CTABg = alloc((size_t)2048 * 1024);
  float* CTABc = alloc((size_t)2048 * 512);
  float* XWg   = alloc((size_t)16384 * 1024);
  float* XWc   = alloc((size_t)16384 * 512);
  float* Hw    = alloc(512 * 512);
  unsigned short* WhgBF = (unsigned short*)alloc(512 * 1024 / 2); // word gate W
  unsigned short* WhcBF = (unsigned short*)alloc(512 * 512 / 2);  // word cand W
  unsigned short* WgcBF = (unsigned short*)alloc(512 * 1024 / 2); // char gate W
  unsigned short* WccBF = (unsigned short*)alloc(512 * 512 / 2);  // char cand W

  hipMemsetAsync(HcA, 0, (size_t)4096 * 512 * sizeof(float), stream);

  // --- Stage 0: bf16 weight conversions (word + char h-parts) ---
  wconv_k<<<(512 * 1024 + 255) / 256, 256, 0, stream>>>(
      Wg_w + (size_t)1280 * 1024, WhgBF, 512 * 1024);
  wconv_k<<<(512 * 512 + 255) / 256, 256, 0, stream>>>(
      Wc_w + (size_t)1280 * 512, WhcBF, 512 * 512);
  wconv_k<<<(512 * 1024 + 255) / 256, 256, 0, stream>>>(
      Wg_c + 128 * 1024, WgcBF, 512 * 1024);
  wconv_k<<<(512 * 512 + 255) / 256, 256, 0, stream>>>(
      Wc_c + 128 * 512, WccBF, 512 * 512);

  // --- Stage A: char x-part tables (fp32) ---
  {
    GemmArgs a{}; a.M = 256; a.N = 1024; a.K = 128;
    a.A = char_emb; a.lda = 128; a.B = Wg_c; a.bias = bg_c; a.Cout = XTABg; a.ldc = 1024;
    gemm_k<A_PLAIN, E_BIAS><<<dim3(1024 / TILE, 256 / TILE), 256, 0, stream>>>(a);
    GemmArgs c{}; c.M = 256; c.N = 512; c.K = 128;
    c.A = char_emb; c.lda = 128; c.B = Wc_c; c.bias = bc_c; c.Cout = XTABc; c.ldc = 512;
    gemm_k<A_PLAIN, E_BIAS><<<dim3(512 / TILE, 256 / TILE), 256, 0, stream>>>(c);
  }

  // --- Stage B: char bi-GRU, MFMA bf16 GEMM loop ---
  float* hcur = HcA; float* hnext = HcB;
  for (int t = 0; t < 16; ++t) {
    cgemm_mfma<128, 0><<<dim3(1024 / 128, 4096 / 64), 256, 0, stream>>>(
        hcur, nullptr, WgcBF, 1024, XTABg, charseqs, charseq_lens, t, nullptr,
        Gc, 1024);
    cgemm_mfma<64, 1><<<dim3(512 / 64, 4096 / 64), 256, 0, stream>>>(
        hcur, Gc, WccBF, 512, XTABc, charseqs, charseq_lens, t, hcur,
        hnext, 512);
    float* tmp = hcur; hcur = hnext; hnext = tmp;
  }
  // after 16 steps hcur == HcA

  // --- Stage C: per-wordform x-part (fp32) ---
  {
    GemmArgs a{}; a.M = 2048; a.N = 1024; a.K = 1024;
    a.A = hcur; a.B = Wg_w; a.bias = bg_w; a.Cout = CTABg; a.ldc = 1024;
    gemm_k<A_CHARSTATE, E_BIAS><<<dim3(1024 / TILE, 2048 / TILE), 256, 0, stream>>>(a);
    GemmArgs c{}; c.M = 2048; c.N = 512; c.K = 1024;
    c.A = hcur; c.B = Wc_w; c.bias = bc_w; c.Cout = CTABc; c.ldc = 512;
    gemm_k<A_CHARSTATE, E_BIAS><<<dim3(512 / TILE, 2048 / TILE), 256, 0, stream>>>(c);
  }

  // --- Stage D: word-emb x-part + CTAB gather (fp32) ---
  {
    GemmArgs a{}; a.M = 16384; a.N = 1024; a.K = 256;
    a.A = word_emb; a.lda = 256; a.arows = word_ids; a.B = Wg_w + (size_t)1024 * 1024;
    a.XT = CTABg; a.ldxt = 1024; a.cidx = charseq_ids; a.Cout = XWg; a.ldc = 1024;
    gemm_k<A_GATHER, E_XW><<<dim3(1024 / TILE, 16384 / TILE), 256, 0, stream>>>(a);
    GemmArgs c{}; c.M = 16384; c.N = 512; c.K = 256;
    c.A = word_emb; c.lda = 256; c.arows = word_ids; c.B = Wc_w + (size_t)1024 * 512;
    c.XT = CTABc; c.ldxt = 512; c.cidx = charseq_ids; c.Cout = XWc; c.ldc = 512;
    gemm_k<A_GATHER, E_XW><<<dim3(512 / TILE, 16384 / TILE), 256, 0, stream>>>(c);
  }

  // --- Stage E: fused word bi-GRU, bf16 weights (R=2, 256 blocks x 256 thr) ---
  gru_word_bf<2, 256, 64><<<256, 256, 0, stream>>>(
      WhgBF, WhcBF, XWg, XWc, sentence_lens, Hw);

  // --- Stage F: FC head ---
  head_k<<<256, 64, 0, stream>>>(Hw, W1, b1, W2, b2, out);
}

// Round 23
// 3496.747 us; speedup vs baseline: 2.0792x; 1.0377x over previous
//
#include <hip/hip_runtime.h>
#include <math.h>

// ---------------------------------------------------------------------------
// Hierarchical bi-GRU (char bi-GRU -> word bi-GRU -> FC head).
//
// r23 = r22 (= r15, measured best 3628us) + two low-risk edits:
//  1. word persistent kernel: per-step context (x-row offsets, mask) moved
//     from LDS+barrier to redundant per-thread registers -> 2 barriers/step
//     instead of 3 (math bitwise-identical).
//  2. Stage D (word-emb x-part, was fp32 gemm_k ~318us) -> bf16 MFMA via the
//     proven cgemm_mfma generalized with AM=gather / EM=XW epilogue.
//
//   gates = sigmoid(x@Wg_x + h@Wg_h + bg)      (x-part precomputed)
//   c     = tanh  (x@Wc_x + (r*h)@Wc_h + bc)
//   h'    = mask ? u*h + (1-u)*c : h
// ---------------------------------------------------------------------------

#define TILE 64
#define BKK 16

typedef __attribute__((ext_vector_type(8))) short bshort8;
typedef __attribute__((ext_vector_type(4))) float f32x4;

enum AMode { A_PLAIN = 0, A_CHARSTATE = 1 };
enum EMode { E_BIAS = 0 };

struct GemmArgs {
  int M, N, K;
  const float* A; int lda;
  const float* B;
  const float* bias;
  float* Cout; int ldc;
};

__device__ __forceinline__ float sigmoidf_(float x) { return 1.0f / (1.0f + expf(-x)); }
__device__ __forceinline__ float bf2f_(unsigned short u) {
  return __uint_as_float((unsigned int)u << 16);
}
__device__ __forceinline__ unsigned short f2bf_(float f) {
  const unsigned int u = __float_as_uint(f);
  return (unsigned short)((u + 0x7FFFu + ((u >> 16) & 1u)) >> 16);
}

// --------------------------- fp32 64x64 tile GEMM (stages A, C) -------------
template<int AM, int EM>
__global__ __launch_bounds__(256) void gemm_k(GemmArgs p) {
  __shared__ float As[BKK][TILE];
  __shared__ float Bs[BKK][TILE];
  const int tid = threadIdx.x;
  const int tx = tid & 15, ty = tid >> 4;
  const int m0 = blockIdx.y * TILE, n0 = blockIdx.x * TILE;
  const int la_r = tid >> 2, la_k = (tid & 3) << 2;
  const int lb_k = tid >> 4, lb_n = (tid & 15) << 2;

  float acc[4][4] = {};

  for (int k0 = 0; k0 < p.K; k0 += BKK) {
    float4 av;
    const int m = m0 + la_r;
    const int k = k0 + la_k;
    if constexpr (AM == A_PLAIN) {
      av = *reinterpret_cast<const float4*>(p.A + (size_t)m * p.lda + k);
    } else { // A_CHARSTATE
      const float* ap = (k < 512) ? (p.A + (size_t)m * 512 + k)
                                  : (p.A + (size_t)(2048 + m) * 512 + (k - 512));
      av = *reinterpret_cast<const float4*>(ap);
    }
    As[la_k + 0][la_r] = av.x;
    As[la_k + 1][la_r] = av.y;
    As[la_k + 2][la_r] = av.z;
    As[la_k + 3][la_r] = av.w;
    float4 bv = *reinterpret_cast<const float4*>(p.B + (size_t)(k0 + lb_k) * p.N + n0 + lb_n);
    *reinterpret_cast<float4*>(&Bs[lb_k][lb_n]) = bv;
    __syncthreads();
#pragma unroll
    for (int kk = 0; kk < BKK; ++kk) {
      float4 a = *reinterpret_cast<const float4*>(&As[kk][ty << 2]);
      float4 b = *reinterpret_cast<const float4*>(&Bs[kk][tx << 2]);
      acc[0][0] += a.x * b.x; acc[0][1] += a.x * b.y; acc[0][2] += a.x * b.z; acc[0][3] += a.x * b.w;
      acc[1][0] += a.y * b.x; acc[1][1] += a.y * b.y; acc[1][2] += a.y * b.z; acc[1][3] += a.y * b.w;
      acc[2][0] += a.z * b.x; acc[2][1] += a.z * b.y; acc[2][2] += a.z * b.z; acc[2][3] += a.z * b.w;
      acc[3][0] += a.w * b.x; acc[3][1] += a.w * b.y; acc[3][2] += a.w * b.z; acc[3][3] += a.w * b.w;
    }
    __syncthreads();
  }

  const int rbase = m0 + (ty << 2);
  const int cbase = n0 + (tx << 2);
#pragma unroll
  for (int i = 0; i < 4; ++i) {
    const int row = rbase + i;
#pragma unroll
    for (int j = 0; j < 4; ++j) {
      const int col = cbase + j;
      p.Cout[(size_t)row * p.ldc + col] = acc[i][j] + p.bias[col];
    }
  }
}

// fp32 -> bf16 (RNE) weight conversion
__global__ __launch_bounds__(256) void wconv_k(const float* __restrict__ src,
                                               unsigned short* __restrict__ dst,
                                               int n) {
  const int i = blockIdx.x * 256 + threadIdx.x;
  if (i < n) dst[i] = f2bf_(src[i]);
}

// ---------------------------------------------------------------------------
// Recurrent/gather GEMM via bf16 MFMA. BM=64 rows, BN cols, BK=32, 256 thr.
// AM: 0 = plain rows of Ain (stride lda); 1 = (r*h) rows (G gate, lda=512);
//     2 = gathered rows Ain[arows[row]] (stride lda).
// EM: 0 = char gate (sigmoid + XT[seqs]); 1 = char cand (tanh + masked
//     update); 2 = XW (plain + XT[cidx[row]]).
// Fragment maps m89-verified (A row=lane&15 k=8*(lane>>4)+j; D col=lane&15,
// row=(lane>>4)*4+reg).
// ---------------------------------------------------------------------------
template<int BN, int AM, int EM>
__global__ __launch_bounds__(256) void cgemm_mfma(
    const float* __restrict__ Ain, int lda,
    const float* __restrict__ G,          // AM=1 r-gates / EM=1 u-gates [M][1024]
    const unsigned short* __restrict__ Bw,// bf16 weights [K][ldb]
    int ldb, int K,
    const float* __restrict__ XT, int ldxt,
    const int* __restrict__ seqs,         // EM<2: [2048][16]
    const int* __restrict__ lens,         // EM<2: [2048]
    int t,
    const int* __restrict__ arows,        // AM=2 gather indices
    const int* __restrict__ cidx,         // EM=2 table indices
    const float* __restrict__ Hin,        // EM=1: h
    float* __restrict__ Cout, int ldc) {
  __shared__ unsigned short As[64][40];
  __shared__ unsigned short Bs[BN][40];
  __shared__ int xo_s[64];
  __shared__ int msk_s[64];

  const int tid = threadIdx.x;
  const int m0 = blockIdx.y * 64;
  const int n0 = blockIdx.x * BN;

  if (tid < 64) {
    const int grow = m0 + tid;
    if constexpr (EM == 2) {
      xo_s[tid] = cidx[grow] * ldxt;
      msk_s[tid] = 1;
    } else {
      const int us = grow & 2047;
      const bool dir = grow >= 2048;
      const int len = lens[us];
      int pos = dir ? (len - 1 - t) : t;
      pos = pos < 0 ? 0 : (pos > 15 ? 15 : pos);
      const int ch = seqs[us * 16 + pos];
      xo_s[tid] = ch * ldxt;
      msk_s[tid] = (t < len) ? 1 : 0;
    }
  }

  const int wid = tid >> 6, lane = tid & 63;
  const int lr = lane & 15, lk = (lane >> 4) << 3;
  constexpr int NI = BN / 64;
  const int c0w = wid * (BN / 4);

  f32x4 acc[4][NI];
#pragma unroll
  for (int mi = 0; mi < 4; ++mi)
#pragma unroll
    for (int ni = 0; ni < NI; ++ni) acc[mi][ni] = (f32x4){0.f, 0.f, 0.f, 0.f};

  const int arow = tid >> 2;
  const int akoff = (tid & 3) << 3;
  int agrow = m0 + arow;
  if constexpr (AM == 2) agrow = arows[m0 + arow];

  for (int k0 = 0; k0 < K; k0 += 32) {
    {
      const float* ap = Ain + (size_t)agrow * lda + k0 + akoff;
      float4 a0 = *reinterpret_cast<const float4*>(ap);
      float4 a1 = *reinterpret_cast<const float4*>(ap + 4);
      if constexpr (AM == 1) {  // A = r * h
        const float* gp = G + (size_t)(m0 + arow) * 1024 + k0 + akoff;
        float4 g0 = *reinterpret_cast<const float4*>(gp);
        float4 g1 = *reinterpret_cast<const float4*>(gp + 4);
        a0.x *= g0.x; a0.y *= g0.y; a0.z *= g0.z; a0.w *= g0.w;
        a1.x *= g1.x; a1.y *= g1.y; a1.z *= g1.z; a1.w *= g1.w;
      }
      bshort8 av;
      av[0] = (short)f2bf_(a0.x); av[1] = (short)f2bf_(a0.y);
      av[2] = (short)f2bf_(a0.z); av[3] = (short)f2bf_(a0.w);
      av[4] = (short)f2bf_(a1.x); av[5] = (short)f2bf_(a1.y);
      av[6] = (short)f2bf_(a1.z); av[7] = (short)f2bf_(a1.w);
      *reinterpret_cast<bshort8*>(&As[arow][akoff]) = av;
    }
    if (BN == 128 || tid < 128) {
      const int bc0 = (BN == 128) ? ((tid & 31) << 2) : ((tid & 15) << 2);
      const int bk0 = (BN == 128) ? ((tid >> 5) << 2) : ((tid >> 4) << 2);
      ushort4 b0 = *reinterpret_cast<const ushort4*>(Bw + (size_t)(k0 + bk0 + 0) * ldb + n0 + bc0);
      ushort4 b1 = *reinterpret_cast<const ushort4*>(Bw + (size_t)(k0 + bk0 + 1) * ldb + n0 + bc0);
      ushort4 b2 = *reinterpret_cast<const ushort4*>(Bw + (size_t)(k0 + bk0 + 2) * ldb + n0 + bc0);
      ushort4 b3 = *reinterpret_cast<const ushort4*>(Bw + (size_t)(k0 + bk0 + 3) * ldb + n0 + bc0);
      ushort4 w;
      w.x = b0.x; w.y = b1.x; w.z = b2.x; w.w = b3.x;
      *reinterpret_cast<ushort4*>(&Bs[bc0 + 0][bk0]) = w;
      w.x = b0.y; w.y = b1.y; w.z = b2.y; w.w = b3.y;
      *reinterpret_cast<ushort4*>(&Bs[bc0 + 1][bk0]) = w;
      w.x = b0.z; w.y = b1.z; w.z = b2.z; w.w = b3.z;
      *reinterpret_cast<ushort4*>(&Bs[bc0 + 2][bk0]) = w;
      w.x = b0.w; w.y = b1.w; w.z = b2.w; w.w = b3.w;
      *reinterpret_cast<ushort4*>(&Bs[bc0 + 3][bk0]) = w;
    }
    __syncthreads();

    bshort8 af[4];
#pragma unroll
    for (int mi = 0; mi < 4; ++mi)
      af[mi] = *reinterpret_cast<const bshort8*>(&As[mi * 16 + lr][lk]);
#pragma unroll
    for (int ni = 0; ni < NI; ++ni) {
      const bshort8 bf = *reinterpret_cast<const bshort8*>(&Bs[c0w + ni * 16 + lr][lk]);
#pragma unroll
      for (int mi = 0; mi < 4; ++mi)
        acc[mi][ni] = __builtin_amdgcn_mfma_f32_16x16x32_bf16(af[mi], bf, acc[mi][ni], 0, 0, 0);
    }
    __syncthreads();
  }

  const int rq = lane >> 4;
#pragma unroll
  for (int mi = 0; mi < 4; ++mi) {
#pragma unroll
    for (int ni = 0; ni < NI; ++ni) {
#pragma unroll
      for (int reg = 0; reg < 4; ++reg) {
        const int lrow = mi * 16 + rq * 4 + reg;
        const int grow = m0 + lrow;
        const int col = n0 + c0w + ni * 16 + lr;
        const float v = acc[mi][ni][reg];
        if constexpr (EM == 0) {
          Cout[(size_t)grow * ldc + col] = sigmoidf_(v + XT[xo_s[lrow] + col]);
        } else if constexpr (EM == 1) {
          const float cv = tanhf(v + XT[xo_s[lrow] + col]);
          const float u = G[(size_t)grow * 1024 + 512 + col];
          const float h = Hin[(size_t)grow * 512 + col];
          Cout[(size_t)grow * ldc + col] = msk_s[lrow] ? (u * h + (1.0f - u) * cv) : h;
        } else { // EM == 2
          Cout[(size_t)grow * ldc + col] = v + XT[xo_s[lrow] + col];
        }
      }
    }
  }
}

// ---------------------------------------------------------------------------
// Fused persistent word GRU, bf16 weights (r12 config: R=2, 256 blocks x 256
// threads, row-major wave-coalesced weight loads). r23: per-step context in
// REGISTERS (no LDS write + barrier) -> 2 barriers/step. Math identical.
// ---------------------------------------------------------------------------
template<int R, int NU, int TT>
__global__ __launch_bounds__(256) void gru_word_bf(
    const unsigned short* __restrict__ Whg,  // [512,1024] bf16
    const unsigned short* __restrict__ Whc,  // [512,512]  bf16
    const float* __restrict__ Xg,            // [NU*TT,1024] (bias folded)
    const float* __restrict__ Xc,            // [NU*TT,512]
    const int*   __restrict__ lens,          // [NU]
    float* __restrict__ Hout)                // [2*NU, 512]
{
  __shared__ float h_s [R][512];
  __shared__ float rh_s[R][512];
  __shared__ float u_s [R][512];

  const int tid  = threadIdx.x;
  const int row0 = blockIdx.x * R;
  const int us0  = row0 & (NU - 1);
  const bool bw  = row0 >= NU;

  for (int i = tid; i < R * 512; i += 256) h_s[i >> 9][i & 511] = 0.0f;
  int lenr[R];
#pragma unroll
  for (int r = 0; r < R; ++r) lenr[r] = lens[us0 + r];
  __syncthreads();

  const int c0 = tid << 2;   // phase-1: 4 gate cols of 1024
  const int c2 = tid << 1;   // phase-2: 2 cand cols of 512

  for (int t = 0; t < TT; ++t) {
    int xog[R], xoc[R], msk[R];
#pragma unroll
    for (int r = 0; r < R; ++r) {
      int pos = bw ? (lenr[r] - 1 - t) : t;
      pos = pos < 0 ? 0 : (pos > TT - 1 ? TT - 1 : pos);
      const int xr = (us0 + r) * TT + pos;
      xog[r] = xr * 1024;
      xoc[r] = xr * 512;
      msk[r] = (t < lenr[r]) ? 1 : 0;
    }

    // ---- phase 1: gates = sigmoid(h @ Whg + Xg); rh / u -> LDS ----
    float4 acc[R];
#pragma unroll
    for (int r = 0; r < R; ++r) acc[r] = make_float4(0.f, 0.f, 0.f, 0.f);
#pragma unroll 2
    for (int k0 = 0; k0 < 512; k0 += 4) {
      ushort4 wu[4];
#pragma unroll
      for (int i = 0; i < 4; ++i)
        wu[i] = *reinterpret_cast<const ushort4*>(Whg + (size_t)(k0 + i) * 1024 + c0);
      float4 hv[R];
#pragma unroll
      for (int r = 0; r < R; ++r)
        hv[r] = *reinterpret_cast<const float4*>(&h_s[r][k0]);
#pragma unroll
      for (int i = 0; i < 4; ++i) {
        const float wx = bf2f_(wu[i].x), wy = bf2f_(wu[i].y);
        const float wz = bf2f_(wu[i].z), ww = bf2f_(wu[i].w);
#pragma unroll
        for (int r = 0; r < R; ++r) {
          const float h = (i == 0) ? hv[r].x : (i == 1) ? hv[r].y : (i == 2) ? hv[r].z : hv[r].w;
          acc[r].x += h * wx; acc[r].y += h * wy;
          acc[r].z += h * wz; acc[r].w += h * ww;
        }
      }
    }
#pragma unroll
    for (int r = 0; r < R; ++r) {
      const float4 x = *reinterpret_cast<const float4*>(Xg + xog[r] + c0);
      float4 g;
      g.x = sigmoidf_(acc[r].x + x.x);
      g.y = sigmoidf_(acc[r].y + x.y);
      g.z = sigmoidf_(acc[r].z + x.z);
      g.w = sigmoidf_(acc[r].w + x.w);
      if (c0 < 512) {        // r-gate cols -> rh = r * h
        const float4 hh = *reinterpret_cast<const float4*>(&h_s[r][c0]);
        rh_s[r][c0 + 0] = g.x * hh.x;
        rh_s[r][c0 + 1] = g.y * hh.y;
        rh_s[r][c0 + 2] = g.z * hh.z;
        rh_s[r][c0 + 3] = g.w * hh.w;
      } else {               // u-gate cols
        u_s[r][c0 - 512 + 0] = g.x;
        u_s[r][c0 - 512 + 1] = g.y;
        u_s[r][c0 - 512 + 2] = g.z;
        u_s[r][c0 - 512 + 3] = g.w;
      }
    }
    __syncthreads();

    // ---- phase 2: c = tanh(rh @ Whc + Xc); h' = mask ? u*h+(1-u)*c : h ----
    float2 acc2[R];
#pragma unroll
    for (int r = 0; r < R; ++r) acc2[r] = make_float2(0.f, 0.f);
#pragma unroll 2
    for (int k0 = 0; k0 < 512; k0 += 4) {
      ushort2 wu[4];
#pragma unroll
      for (int i = 0; i < 4; ++i)
        wu[i] = *reinterpret_cast<const ushort2*>(Whc + (size_t)(k0 + i) * 512 + c2);
      float4 rv[R];
#pragma unroll
      for (int r = 0; r < R; ++r)
        rv[r] = *reinterpret_cast<const float4*>(&rh_s[r][k0]);
#pragma unroll
      for (int i = 0; i < 4; ++i) {
        const float wx = bf2f_(wu[i].x), wy = bf2f_(wu[i].y);
#pragma unroll
        for (int r = 0; r < R; ++r) {
          const float rvv = (i == 0) ? rv[r].x : (i == 1) ? rv[r].y : (i == 2) ? rv[r].z : rv[r].w;
          acc2[r].x += rvv * wx; acc2[r].y += rvv * wy;
        }
      }
    }
#pragma unroll
    for (int r = 0; r < R; ++r) {
      const float2 x = *reinterpret_cast<const float2*>(Xc + xoc[r] + c2);
      const float cx = tanhf(acc2[r].x + x.x);
      const float cy = tanhf(acc2[r].y + x.y);
      if (msk[r]) {
        const float ux = u_s[r][c2], uy = u_s[r][c2 + 1];
        const float hx = h_s[r][c2], hy = h_s[r][c2 + 1];
        h_s[r][c2]     = ux * hx + (1.0f - ux) * cx;
        h_s[r][c2 + 1] = uy * hy + (1.0f - uy) * cy;
      }
    }
    __syncthreads();
  }

  for (int i = tid; i < R * 512; i += 256)
    Hout[(size_t)(row0 + (i >> 9)) * 512 + (i & 511)] = h_s[i >> 9][i & 511];
}

// FC head
__global__ __launch_bounds__(64) void head_k(const float* __restrict__ Hw,
                                             const float* __restrict__ W1,
                                             const float* __restrict__ b1,
                                             const float* __restrict__ W2,
                                             const float* __restrict__ b2,
                                             float* __restrict__ out) {
  __shared__ float s[1024];
  __shared__ float hid[64];
  const int b = blockIdx.x;
  const int tid = threadIdx.x;
  for (int k = tid; k < 512; k += 64) {
    s[k]       = Hw[(size_t)b * 512 + k];
    s[512 + k] = Hw[(size_t)(256 + b) * 512 + k];
  }
  __syncthreads();
  float acc = b1[tid];
  for (int k = 0; k < 1024; ++k) acc += s[k] * W1[k * 64 + tid];
  acc = acc > 0.0f ? acc : 0.2f * acc;
  hid[tid] = acc;
  __syncthreads();
  if (tid < 2) {
    float a = b2[tid];
    for (int k = 0; k < 64; ++k) a += hid[k] * W2[k * 2 + tid];
    out[b * 2 + tid] = a;
  }
}

extern "C" void kernel_launch(void* const* d_in, const int* in_sizes, int n_in,
                              void* d_out, int out_size, void* d_ws, size_t ws_size,
                              hipStream_t stream) {
  const int*   charseqs      = (const int*)d_in[0];
  const int*   charseq_lens  = (const int*)d_in[1];
  const int*   charseq_ids   = (const int*)d_in[2];
  const int*   word_ids      = (const int*)d_in[3];
  const int*   sentence_lens = (const int*)d_in[4];
  const float* char_emb      = (const float*)d_in[5];
  const float* word_emb      = (const float*)d_in[6];
  const float* Wg_c          = (const float*)d_in[7];
  const float* bg_c          = (const float*)d_in[8];
  const float* Wc_c          = (const float*)d_in[9];
  const float* bc_c          = (const float*)d_in[10];
  const float* Wg_w          = (const float*)d_in[11];
  const float* bg_w          = (const float*)d_in[12];
  const float* Wc_w          = (const float*)d_in[13];
  const float* bc_w          = (const float*)d_in[14];
  const float* W1            = (const float*)d_in[15];
  const float* b1            = (const float*)d_in[16];
  const float* W2            = (const float*)d_in[17];
  const float* b2            = (const float*)d_in[18];
  float* out = (float*)d_out;

  float* ws = (float*)d_ws;
  size_t off = 0;
  auto alloc = [&](size_t n) { float* p = ws + off; off += n; return p; };
  float* XTABg = alloc(256 * 1024);
  float* XTABc = alloc(256 * 512);
  float* HcA   = alloc((size_t)4096 * 512);
  float* HcB   = alloc((size_t)4096 * 512);
  float* Gc    = alloc((size_t)4096 * 1024);
  float* CTABg = alloc((size_t)2048 * 1024);
  float* CTABc = alloc((size_t)2048 * 512);
  float* XWg   = alloc((size_t)16384 * 1024);
  float* XWc   = alloc((size_t)16384 * 512);
  float* Hw    = alloc(512 * 512);
  unsigned short* WhgBF = (unsigned short*)alloc(512 * 1024 / 2); // word gate h-part
  unsigned short* WhcBF = (unsigned short*)alloc(512 * 512 / 2);  // word cand h-part
  unsigned short* WgcBF = (unsigned short*)alloc(512 * 1024 / 2); // char gate h-part
  unsigned short* WccBF = (unsigned short*)alloc(512 * 512 / 2);  // char cand h-part
  unsigned short* WgwBF = (unsigned short*)alloc(256 * 1024 / 2); // word gate emb-part
  unsigned short* WcwBF = (unsigned short*)alloc(256 * 512 / 2);  // word cand emb-part

  hipMemsetAsync(HcA, 0, (size_t)4096 * 512 * sizeof(float), stream);

  // --- Stage 0: bf16 weight conversions ---
  wconv_k<<<(512 * 1024 + 255) / 256, 256, 0, stream>>>(
      Wg_w + (size_t)1280 * 1024, WhgBF, 512 * 1024);
  wconv_k<<<(512 * 512 + 255) / 256, 256, 0, stream>>>(
      Wc_w + (size_t)1280 * 512, WhcBF, 512 * 512);
  wconv_k<<<(512 * 1024 + 255) / 256, 256, 0, stream>>>(
      Wg_c + 128 * 1024, WgcBF, 512 * 1024);
  wconv_k<<<(512 * 512 + 255) / 256, 256, 0, stream>>>(
      Wc_c + 128 * 512, WccBF, 512 * 512);
  wconv_k<<<(256 * 1024 + 255) / 256, 256, 0, stream>>>(
      Wg_w + (size_t)1024 * 1024, WgwBF, 256 * 1024);
  wconv_k<<<(256 * 512 + 255) / 256, 256, 0, stream>>>(
      Wc_w + (size_t)1024 * 512, WcwBF, 256 * 512);

  // --- Stage A: char x-part tables (fp32) ---
  {
    GemmArgs a{}; a.M = 256; a.N = 1024; a.K = 128;
    a.A = char_emb; a.lda = 128; a.B = Wg_c; a.bias = bg_c; a.Cout = XTABg; a.ldc = 1024;
    gemm_k<A_PLAIN, E_BIAS><<<dim3(1024 / TILE, 256 / TILE), 256, 0, stream>>>(a);
    GemmArgs c{}; c.M = 256; c.N = 512; c.K = 128;
    c.A = char_emb; c.lda = 128; c.B = Wc_c; c.bias = bc_c; c.Cout = XTABc; c.ldc = 512;
    gemm_k<A_PLAIN, E_BIAS><<<dim3(512 / TILE, 256 / TILE), 256, 0, stream>>>(c);
  }

  // --- Stage B: char bi-GRU, MFMA bf16 GEMM loop ---
  float* hcur = HcA; float* hnext = HcB;
  for (int t = 0; t < 16; ++t) {
    cgemm_mfma<128, 0, 0><<<dim3(1024 / 128, 4096 / 64), 256, 0, stream>>>(
        hcur, 512, nullptr, WgcBF, 1024, 512, XTABg, 1024,
        charseqs, charseq_lens, t, nullptr, nullptr, nullptr, Gc, 1024);
    cgemm_mfma<64, 1, 1><<<dim3(512 / 64, 4096 / 64), 256, 0, stream>>>(
        hcur, 512, Gc, WccBF, 512, 512, XTABc, 512,
        charseqs, charseq_lens, t, nullptr, nullptr, hcur, hnext, 512);
    float* tmp = hcur; hcur = hnext; hnext = tmp;
  }
  // after 16 steps hcur == HcA

  // --- Stage C: per-wordform x-part (fp32) ---
  {
    GemmArgs a{}; a.M = 2048; a.N = 1024; a.K = 1024;
    a.A = hcur; a.B = Wg_w; a.bias = bg_w; a.Cout = CTABg; a.ldc = 1024;
    gemm_k<A_CHARSTATE, E_BIAS><<<dim3(1024 / TILE, 2048 / TILE), 256, 0, stream>>>(a);
    GemmArgs c{}; c.M = 2048; c.N = 512; c.K = 1024;
    c.A = hcur; c.B = Wc_w; c.bias = bc_w; c.Cout = CTABc; c.ldc = 512;
    gemm_k<A_CHARSTATE, E_BIAS><<<dim3(512 / TILE, 2048 / TILE), 256, 0, stream>>>(c);
  }

  // --- Stage D: word-emb x-part + CTAB gather (bf16 MFMA, r23) ---
  {
    cgemm_mfma<128, 2, 2><<<dim3(1024 / 128, 16384 / 64), 256, 0, stream>>>(
        word_emb, 256, nullptr, WgwBF, 1024, 256, CTABg, 1024,
        nullptr, nullptr, 0, word_ids, charseq_ids, nullptr, XWg, 1024);
    cgemm_mfma<64, 2, 2><<<dim3(512 / 64, 16384 / 64), 256, 0, stream>>>(
        word_emb, 256, nullptr, WcwBF, 512, 256, CTABc, 512,
        nullptr, nullptr, 0, word_ids, charseq_ids, nullptr, XWc, 512);
  }

  // --- Stage E: fused word bi-GRU, bf16 weights (R=2, 256 blocks x 256 thr) ---
  gru_word_bf<2, 256, 64><<<256, 256, 0, stream>>>(
      WhgBF, WhcBF, XWg, XWc, sentence_lens, Hw);

  // --- Stage F: FC head ---
  head_k<<<256, 64, 0, stream>>>(Hw, W1, b1, W2, b2, out);
}

// Round 24
// 3430.429 us; speedup vs baseline: 2.1194x; 1.0193x over previous
//
#include <hip/hip_runtime.h>
#include <math.h>

// ---------------------------------------------------------------------------
// Hierarchical bi-GRU (char bi-GRU -> word bi-GRU -> FC head).
//
// r24 = r23 (best, 3497us) + Stage C (per-wordform x-part, last big fp32
// GEMM pair ~180us) moved to bf16 MFMA: cgemm_mfma gains AM=3 (A = concat
// char-state rows) and EM=3 (plain +bias epilogue). All GEMMs now MFMA;
// word recurrence (2430us) at its measured structural floor.
//
//   gates = sigmoid(x@Wg_x + h@Wg_h + bg)      (x-part precomputed)
//   c     = tanh  (x@Wc_x + (r*h)@Wc_h + bc)
//   h'    = mask ? u*h + (1-u)*c : h
// ---------------------------------------------------------------------------

#define TILE 64
#define BKK 16

typedef __attribute__((ext_vector_type(8))) short bshort8;
typedef __attribute__((ext_vector_type(4))) float f32x4;

struct GemmArgs {
  int M, N, K;
  const float* A; int lda;
  const float* B;
  const float* bias;
  float* Cout; int ldc;
};

__device__ __forceinline__ float sigmoidf_(float x) { return 1.0f / (1.0f + expf(-x)); }
__device__ __forceinline__ float bf2f_(unsigned short u) {
  return __uint_as_float((unsigned int)u << 16);
}
__device__ __forceinline__ unsigned short f2bf_(float f) {
  const unsigned int u = __float_as_uint(f);
  return (unsigned short)((u + 0x7FFFu + ((u >> 16) & 1u)) >> 16);
}

// --------------------------- fp32 64x64 tile GEMM (stage A only) ------------
__global__ __launch_bounds__(256) void gemm_k(GemmArgs p) {
  __shared__ float As[BKK][TILE];
  __shared__ float Bs[BKK][TILE];
  const int tid = threadIdx.x;
  const int tx = tid & 15, ty = tid >> 4;
  const int m0 = blockIdx.y * TILE, n0 = blockIdx.x * TILE;
  const int la_r = tid >> 2, la_k = (tid & 3) << 2;
  const int lb_k = tid >> 4, lb_n = (tid & 15) << 2;

  float acc[4][4] = {};

  for (int k0 = 0; k0 < p.K; k0 += BKK) {
    const int m = m0 + la_r;
    const int k = k0 + la_k;
    float4 av = *reinterpret_cast<const float4*>(p.A + (size_t)m * p.lda + k);
    As[la_k + 0][la_r] = av.x;
    As[la_k + 1][la_r] = av.y;
    As[la_k + 2][la_r] = av.z;
    As[la_k + 3][la_r] = av.w;
    float4 bv = *reinterpret_cast<const float4*>(p.B + (size_t)(k0 + lb_k) * p.N + n0 + lb_n);
    *reinterpret_cast<float4*>(&Bs[lb_k][lb_n]) = bv;
    __syncthreads();
#pragma unroll
    for (int kk = 0; kk < BKK; ++kk) {
      float4 a = *reinterpret_cast<const float4*>(&As[kk][ty << 2]);
      float4 b = *reinterpret_cast<const float4*>(&Bs[kk][tx << 2]);
      acc[0][0] += a.x * b.x; acc[0][1] += a.x * b.y; acc[0][2] += a.x * b.z; acc[0][3] += a.x * b.w;
      acc[1][0] += a.y * b.x; acc[1][1] += a.y * b.y; acc[1][2] += a.y * b.z; acc[1][3] += a.y * b.w;
      acc[2][0] += a.z * b.x; acc[2][1] += a.z * b.y; acc[2][2] += a.z * b.z; acc[2][3] += a.z * b.w;
      acc[3][0] += a.w * b.x; acc[3][1] += a.w * b.y; acc[3][2] += a.w * b.z; acc[3][3] += a.w * b.w;
    }
    __syncthreads();
  }

  const int rbase = m0 + (ty << 2);
  const int cbase = n0 + (tx << 2);
#pragma unroll
  for (int i = 0; i < 4; ++i) {
    const int row = rbase + i;
#pragma unroll
    for (int j = 0; j < 4; ++j) {
      const int col = cbase + j;
      p.Cout[(size_t)row * p.ldc + col] = acc[i][j] + p.bias[col];
    }
  }
}

// fp32 -> bf16 (RNE) weight conversion
__global__ __launch_bounds__(256) void wconv_k(const float* __restrict__ src,
                                               unsigned short* __restrict__ dst,
                                               int n) {
  const int i = blockIdx.x * 256 + threadIdx.x;
  if (i < n) dst[i] = f2bf_(src[i]);
}

// ---------------------------------------------------------------------------
// Unified GEMM via bf16 MFMA. BM=64 rows, BN cols, BK=32, 256 thr = 4 waves.
// AM: 0 = plain rows of Ain (stride lda); 1 = (r*h) rows (G gates, lda=512);
//     2 = gathered rows Ain[arows[row]]; 3 = concat char-state rows
//         (k<512: Ain[row], k>=512: Ain[2048+row], lda=512).
// EM: 0 = char gate (sigmoid + XT[seqs-lookup]); 1 = char cand (tanh +
//     masked h-update); 2 = +XT[cidx[row]]; 3 = +bias[col] (XT=bias).
// Fragment maps m89-verified.
// ---------------------------------------------------------------------------
template<int BN, int AM, int EM>
__global__ __launch_bounds__(256) void cgemm_mfma(
    const float* __restrict__ Ain, int lda,
    const float* __restrict__ G,          // AM=1 r-gates / EM=1 u-gates [M][1024]
    const unsigned short* __restrict__ Bw,// bf16 weights [K][ldb]
    int ldb, int K,
    const float* __restrict__ XT, int ldxt,
    const int* __restrict__ seqs,         // EM<2: [2048][16]
    const int* __restrict__ lens,         // EM<2: [2048]
    int t,
    const int* __restrict__ arows,        // AM=2 gather indices
    const int* __restrict__ cidx,         // EM=2 table indices
    const float* __restrict__ Hin,        // EM=1: h
    float* __restrict__ Cout, int ldc) {
  __shared__ unsigned short As[64][40];
  __shared__ unsigned short Bs[BN][40];
  __shared__ int xo_s[64];
  __shared__ int msk_s[64];

  const int tid = threadIdx.x;
  const int m0 = blockIdx.y * 64;
  const int n0 = blockIdx.x * BN;

  if (tid < 64) {
    const int grow = m0 + tid;
    if constexpr (EM == 2) {
      xo_s[tid] = cidx[grow] * ldxt;
      msk_s[tid] = 1;
    } else if constexpr (EM == 3) {
      xo_s[tid] = 0;
      msk_s[tid] = 1;
    } else {
      const int us = grow & 2047;
      const bool dir = grow >= 2048;
      const int len = lens[us];
      int pos = dir ? (len - 1 - t) : t;
      pos = pos < 0 ? 0 : (pos > 15 ? 15 : pos);
      const int ch = seqs[us * 16 + pos];
      xo_s[tid] = ch * ldxt;
      msk_s[tid] = (t < len) ? 1 : 0;
    }
  }

  const int wid = tid >> 6, lane = tid & 63;
  const int lr = lane & 15, lk = (lane >> 4) << 3;
  constexpr int NI = BN / 64;
  const int c0w = wid * (BN / 4);

  f32x4 acc[4][NI];
#pragma unroll
  for (int mi = 0; mi < 4; ++mi)
#pragma unroll
    for (int ni = 0; ni < NI; ++ni) acc[mi][ni] = (f32x4){0.f, 0.f, 0.f, 0.f};

  const int arow = tid >> 2;
  const int akoff = (tid & 3) << 3;
  int agrow = m0 + arow;
  if constexpr (AM == 2) agrow = arows[m0 + arow];

  for (int k0 = 0; k0 < K; k0 += 32) {
    {
      const int k = k0 + akoff;
      const float* ap;
      if constexpr (AM == 3) {
        ap = (k < 512) ? (Ain + (size_t)(m0 + arow) * 512 + k)
                       : (Ain + (size_t)(2048 + m0 + arow) * 512 + (k - 512));
      } else {
        ap = Ain + (size_t)agrow * lda + k;
      }
      float4 a0 = *reinterpret_cast<const float4*>(ap);
      float4 a1 = *reinterpret_cast<const float4*>(ap + 4);
      if constexpr (AM == 1) {  // A = r * h
        const float* gp = G + (size_t)(m0 + arow) * 1024 + k0 + akoff;
        float4 g0 = *reinterpret_cast<const float4*>(gp);
        float4 g1 = *reinterpret_cast<const float4*>(gp + 4);
        a0.x *= g0.x; a0.y *= g0.y; a0.z *= g0.z; a0.w *= g0.w;
        a1.x *= g1.x; a1.y *= g1.y; a1.z *= g1.z; a1.w *= g1.w;
      }
      bshort8 av;
      av[0] = (short)f2bf_(a0.x); av[1] = (short)f2bf_(a0.y);
      av[2] = (short)f2bf_(a0.z); av[3] = (short)f2bf_(a0.w);
      av[4] = (short)f2bf_(a1.x); av[5] = (short)f2bf_(a1.y);
      av[6] = (short)f2bf_(a1.z); av[7] = (short)f2bf_(a1.w);
      *reinterpret_cast<bshort8*>(&As[arow][akoff]) = av;
    }
    if (BN == 128 || tid < 128) {
      const int bc0 = (BN == 128) ? ((tid & 31) << 2) : ((tid & 15) << 2);
      const int bk0 = (BN == 128) ? ((tid >> 5) << 2) : ((tid >> 4) << 2);
      ushort4 b0 = *reinterpret_cast<const ushort4*>(Bw + (size_t)(k0 + bk0 + 0) * ldb + n0 + bc0);
      ushort4 b1 = *reinterpret_cast<const ushort4*>(Bw + (size_t)(k0 + bk0 + 1) * ldb + n0 + bc0);
      ushort4 b2 = *reinterpret_cast<const ushort4*>(Bw + (size_t)(k0 + bk0 + 2) * ldb + n0 + bc0);
      ushort4 b3 = *reinterpret_cast<const ushort4*>(Bw + (size_t)(k0 + bk0 + 3) * ldb + n0 + bc0);
      ushort4 w;
      w.x = b0.x; w.y = b1.x; w.z = b2.x; w.w = b3.x;
      *reinterpret_cast<ushort4*>(&Bs[bc0 + 0][bk0]) = w;
      w.x = b0.y; w.y = b1.y; w.z = b2.y; w.w = b3.y;
      *reinterpret_cast<ushort4*>(&Bs[bc0 + 1][bk0]) = w;
      w.x = b0.z; w.y = b1.z; w.z = b2.z; w.w = b3.z;
      *reinterpret_cast<ushort4*>(&Bs[bc0 + 2][bk0]) = w;
      w.x = b0.w; w.y = b1.w; w.z = b2.w; w.w = b3.w;
      *reinterpret_cast<ushort4*>(&Bs[bc0 + 3][bk0]) = w;
    }
    __syncthreads();

    bshort8 af[4];
#pragma unroll
    for (int mi = 0; mi < 4; ++mi)
      af[mi] = *reinterpret_cast<const bshort8*>(&As[mi * 16 + lr][lk]);
#pragma unroll
    for (int ni = 0; ni < NI; ++ni) {
      const bshort8 bf = *reinterpret_cast<const bshort8*>(&Bs[c0w + ni * 16 + lr][lk]);
#pragma unroll
      for (int mi = 0; mi < 4; ++mi)
        acc[mi][ni] = __builtin_amdgcn_mfma_f32_16x16x32_bf16(af[mi], bf, acc[mi][ni], 0, 0, 0);
    }
    __syncthreads();
  }

  const int rq = lane >> 4;
#pragma unroll
  for (int mi = 0; mi < 4; ++mi) {
#pragma unroll
    for (int ni = 0; ni < NI; ++ni) {
#pragma unroll
      for (int reg = 0; reg < 4; ++reg) {
        const int lrow = mi * 16 + rq * 4 + reg;
        const int grow = m0 + lrow;
        const int col = n0 + c0w + ni * 16 + lr;
        const float v = acc[mi][ni][reg];
        if constexpr (EM == 0) {
          Cout[(size_t)grow * ldc + col] = sigmoidf_(v + XT[xo_s[lrow] + col]);
        } else if constexpr (EM == 1) {
          const float cv = tanhf(v + XT[xo_s[lrow] + col]);
          const float u = G[(size_t)grow * 1024 + 512 + col];
          const float h = Hin[(size_t)grow * 512 + col];
          Cout[(size_t)grow * ldc + col] = msk_s[lrow] ? (u * h + (1.0f - u) * cv) : h;
        } else if constexpr (EM == 2) {
          Cout[(size_t)grow * ldc + col] = v + XT[xo_s[lrow] + col];
        } else { // EM == 3: + bias
          Cout[(size_t)grow * ldc + col] = v + XT[col];
        }
      }
    }
  }
}

// ---------------------------------------------------------------------------
// Fused persistent word GRU, bf16 weights (R=2, 256 blocks x 256 threads,
// row-major wave-coalesced weight loads; per-step context in registers).
// ---------------------------------------------------------------------------
template<int R, int NU, int TT>
__global__ __launch_bounds__(256) void gru_word_bf(
    const unsigned short* __restrict__ Whg,  // [512,1024] bf16
    const unsigned short* __restrict__ Whc,  // [512,512]  bf16
    const float* __restrict__ Xg,            // [NU*TT,1024] (bias folded)
    const float* __restrict__ Xc,            // [NU*TT,512]
    const int*   __restrict__ lens,          // [NU]
    float* __restrict__ Hout)                // [2*NU, 512]
{
  __shared__ float h_s [R][512];
  __shared__ float rh_s[R][512];
  __shared__ float u_s [R][512];

  const int tid  = threadIdx.x;
  const int row0 = blockIdx.x * R;
  const int us0  = row0 & (NU - 1);
  const bool bw  = row0 >= NU;

  for (int i = tid; i < R * 512; i += 256) h_s[i >> 9][i & 511] = 0.0f;
  int lenr[R];
#pragma unroll
  for (int r = 0; r < R; ++r) lenr[r] = lens[us0 + r];
  __syncthreads();

  const int c0 = tid << 2;   // phase-1: 4 gate cols of 1024
  const int c2 = tid << 1;   // phase-2: 2 cand cols of 512

  for (int t = 0; t < TT; ++t) {
    int xog[R], xoc[R], msk[R];
#pragma unroll
    for (int r = 0; r < R; ++r) {
      int pos = bw ? (lenr[r] - 1 - t) : t;
      pos = pos < 0 ? 0 : (pos > TT - 1 ? TT - 1 : pos);
      const int xr = (us0 + r) * TT + pos;
      xog[r] = xr * 1024;
      xoc[r] = xr * 512;
      msk[r] = (t < lenr[r]) ? 1 : 0;
    }

    // ---- phase 1: gates = sigmoid(h @ Whg + Xg); rh / u -> LDS ----
    float4 acc[R];
#pragma unroll
    for (int r = 0; r < R; ++r) acc[r] = make_float4(0.f, 0.f, 0.f, 0.f);
#pragma unroll 2
    for (int k0 = 0; k0 < 512; k0 += 4) {
      ushort4 wu[4];
#pragma unroll
      for (int i = 0; i < 4; ++i)
        wu[i] = *reinterpret_cast<const ushort4*>(Whg + (size_t)(k0 + i) * 1024 + c0);
      float4 hv[R];
#pragma unroll
      for (int r = 0; r < R; ++r)
        hv[r] = *reinterpret_cast<const float4*>(&h_s[r][k0]);
#pragma unroll
      for (int i = 0; i < 4; ++i) {
        const float wx = bf2f_(wu[i].x), wy = bf2f_(wu[i].y);
        const float wz = bf2f_(wu[i].z), ww = bf2f_(wu[i].w);
#pragma unroll
        for (int r = 0; r < R; ++r) {
          const float h = (i == 0) ? hv[r].x : (i == 1) ? hv[r].y : (i == 2) ? hv[r].z : hv[r].w;
          acc[r].x += h * wx; acc[r].y += h * wy;
          acc[r].z += h * wz; acc[r].w += h * ww;
        }
      }
    }
#pragma unroll
    for (int r = 0; r < R; ++r) {
      const float4 x = *reinterpret_cast<const float4*>(Xg + xog[r] + c0);
      float4 g;
      g.x = sigmoidf_(acc[r].x + x.x);
      g.y = sigmoidf_(acc[r].y + x.y);
      g.z = sigmoidf_(acc[r].z + x.z);
      g.w = sigmoidf_(acc[r].w + x.w);
      if (c0 < 512) {        // r-gate cols -> rh = r * h
        const float4 hh = *reinterpret_cast<const float4*>(&h_s[r][c0]);
        rh_s[r][c0 + 0] = g.x * hh.x;
        rh_s[r][c0 + 1] = g.y * hh.y;
        rh_s[r][c0 + 2] = g.z * hh.z;
        rh_s[r][c0 + 3] = g.w * hh.w;
      } else {               // u-gate cols
        u_s[r][c0 - 512 + 0] = g.x;
        u_s[r][c0 - 512 + 1] = g.y;
        u_s[r][c0 - 512 + 2] = g.z;
        u_s[r][c0 - 512 + 3] = g.w;
      }
    }
    __syncthreads();

    // ---- phase 2: c = tanh(rh @ Whc + Xc); h' = mask ? u*h+(1-u)*c : h ----
    float2 acc2[R];
#pragma unroll
    for (int r = 0; r < R; ++r) acc2[r] = make_float2(0.f, 0.f);
#pragma unroll 2
    for (int k0 = 0; k0 < 512; k0 += 4) {
      ushort2 wu[4];
#pragma unroll
      for (int i = 0; i < 4; ++i)
        wu[i] = *reinterpret_cast<const ushort2*>(Whc + (size_t)(k0 + i) * 512 + c2);
      float4 rv[R];
#pragma unroll
      for (int r = 0; r < R; ++r)
        rv[r] = *reinterpret_cast<const float4*>(&rh_s[r][k0]);
#pragma unroll
      for (int i = 0; i < 4; ++i) {
        const float wx = bf2f_(wu[i].x), wy = bf2f_(wu[i].y);
#pragma unroll
        for (int r = 0; r < R; ++r) {
          const float rvv = (i == 0) ? rv[r].x : (i == 1) ? rv[r].y : (i == 2) ? rv[r].z : rv[r].w;
          acc2[r].x += rvv * wx; acc2[r].y += rvv * wy;
        }
      }
    }
#pragma unroll
    for (int r = 0; r < R; ++r) {
      const float2 x = *reinterpret_cast<const float2*>(Xc + xoc[r] + c2);
      const float cx = tanhf(acc2[r].x + x.x);
      const float cy = tanhf(acc2[r].y + x.y);
      if (msk[r]) {
        const float ux = u_s[r][c2], uy = u_s[r][c2 + 1];
        const float hx = h_s[r][c2], hy = h_s[r][c2 + 1];
        h_s[r][c2]     = ux * hx + (1.0f - ux) * cx;
        h_s[r][c2 + 1] = uy * hy + (1.0f - uy) * cy;
      }
    }
    __syncthreads();
  }

  for (int i = tid; i < R * 512; i += 256)
    Hout[(size_t)(row0 + (i >> 9)) * 512 + (i & 511)] = h_s[i >> 9][i & 511];
}

// FC head
__global__ __launch_bounds__(64) void head_k(const float* __restrict__ Hw,
                                             const float* __restrict__ W1,
                                             const float* __restrict__ b1,
                                             const float* __restrict__ W2,
                                             const float* __restrict__ b2,
                                             float* __restrict__ out) {
  __shared__ float s[1024];
  __shared__ float hid[64];
  const int b = blockIdx.x;
  const int tid = threadIdx.x;
  for (int k = tid; k < 512; k += 64) {
    s[k]       = Hw[(size_t)b * 512 + k];
    s[512 + k] = Hw[(size_t)(256 + b) * 512 + k];
  }
  __syncthreads();
  float acc = b1[tid];
  for (int k = 0; k < 1024; ++k) acc += s[k] * W1[k * 64 + tid];
  acc = acc > 0.0f ? acc : 0.2f * acc;
  hid[tid] = acc;
  __syncthreads();
  if (tid < 2) {
    float a = b2[tid];
    for (int k = 0; k < 64; ++k) a += hid[k] * W2[k * 2 + tid];
    out[b * 2 + tid] = a;
  }
}

extern "C" void kernel_launch(void* const* d_in, const int* in_sizes, int n_in,
                              void* d_out, int out_size, void* d_ws, size_t ws_size,
                              hipStream_t stream) {
  const int*   charseqs      = (const int*)d_in[0];
  const int*   charseq_lens  = (const int*)d_in[1];
  const int*   charseq_ids   = (const int*)d_in[2];
  const int*   word_ids      = (const int*)d_in[3];
  const int*   sentence_lens = (const int*)d_in[4];
  const float* char_emb      = (const float*)d_in[5];
  const float* word_emb      = (const float*)d_in[6];
  const float* Wg_c          = (const float*)d_in[7];
  const float* bg_c          = (const float*)d_in[8];
  const float* Wc_c          = (const float*)d_in[9];
  const float* bc_c          = (const float*)d_in[10];
  const float* Wg_w          = (const float*)d_in[11];
  const float* bg_w          = (const float*)d_in[12];
  const float* Wc_w          = (const float*)d_in[13];
  const float* bc_w          = (const float*)d_in[14];
  const float* W1            = (const float*)d_in[15];
  const float* b1            = (const float*)d_in[16];
  const float* W2            = (const float*)d_in[17];
  const float* b2            = (const float*)d_in[18];
  float* out = (float*)d_out;

  float* ws = (float*)d_ws;
  size_t off = 0;
  auto alloc = [&](size_t n) { float* p = ws + off; off += n; return p; };
  float* XTABg = alloc(256 * 1024);
  float* XTABc = alloc(256 * 512);
  float* HcA   = alloc((size_t)4096 * 512);
  float* HcB   = alloc((size_t)4096 * 512);
  float* Gc    = alloc((size_t)4096 * 1024);
  float* CTABg = alloc((size_t)2048 * 1024);
  float* CTABc = alloc((size_t)2048 * 512);
  float* XWg   = alloc((size_t)16384 * 1024);
  float* XWc   = alloc((size_t)16384 * 512);
  float* Hw    = alloc(512 * 512);
  unsigned short* WhgBF = (unsigned short*)alloc(512 * 1024 / 2);  // word gate h-part
  unsigned short* WhcBF = (unsigned short*)alloc(512 * 512 / 2);   // word cand h-part
  unsigned short* WgcBF = (unsigned short*)alloc(512 * 1024 / 2);  // char gate h-part
  unsigned short* WccBF = (unsigned short*)alloc(512 * 512 / 2);   // char cand h-part
  unsigned short* WgwBF = (unsigned short*)alloc(256 * 1024 / 2);  // word gate emb-part
  unsigned short* WcwBF = (unsigned short*)alloc(256 * 512 / 2);   // word cand emb-part
  unsigned short* WgsBF = (unsigned short*)alloc(1024 * 1024 / 2); // word gate cstate-part
  unsigned short* WcsBF = (unsigned short*)alloc(1024 * 512 / 2);  // word cand cstate-part

  hipMemsetAsync(HcA, 0, (size_t)4096 * 512 * sizeof(float), stream);

  // --- Stage 0: bf16 weight conversions ---
  wconv_k<<<(512 * 1024 + 255) / 256, 256, 0, stream>>>(
      Wg_w + (size_t)1280 * 1024, WhgBF, 512 * 1024);
  wconv_k<<<(512 * 512 + 255) / 256, 256, 0, stream>>>(
      Wc_w + (size_t)1280 * 512, WhcBF, 512 * 512);
  wconv_k<<<(512 * 1024 + 255) / 256, 256, 0, stream>>>(
      Wg_c + 128 * 1024, WgcBF, 512 * 1024);
  wconv_k<<<(512 * 512 + 255) / 256, 256, 0, stream>>>(
      Wc_c + 128 * 512, WccBF, 512 * 512);
  wconv_k<<<(256 * 1024 + 255) / 256, 256, 0, stream>>>(
      Wg_w + (size_t)1024 * 1024, WgwBF, 256 * 1024);
  wconv_k<<<(256 * 512 + 255) / 256, 256, 0, stream>>>(
      Wc_w + (size_t)1024 * 512, WcwBF, 256 * 512);
  wconv_k<<<(1024 * 1024 + 255) / 256, 256, 0, stream>>>(
      Wg_w, WgsBF, 1024 * 1024);
  wconv_k<<<(1024 * 512 + 255) / 256, 256, 0, stream>>>(
      Wc_w, WcsBF, 1024 * 512);

  // --- Stage A: char x-part tables (fp32, tiny) ---
  {
    GemmArgs a{}; a.M = 256; a.N = 1024; a.K = 128;
    a.A = char_emb; a.lda = 128; a.B = Wg_c; a.bias = bg_c; a.Cout = XTABg; a.ldc = 1024;
    gemm_k<<<dim3(1024 / TILE, 256 / TILE), 256, 0, stream>>>(a);
    GemmArgs c{}; c.M = 256; c.N = 512; c.K = 128;
    c.A = char_emb; c.lda = 128; c.B = Wc_c; c.bias = bc_c; c.Cout = XTABc; c.ldc = 512;
    gemm_k<<<dim3(512 / TILE, 256 / TILE), 256, 0, stream>>>(c);
  }

  // --- Stage B: char bi-GRU, MFMA bf16 GEMM loop ---
  float* hcur = HcA; float* hnext = HcB;
  for (int t = 0; t < 16; ++t) {
    cgemm_mfma<128, 0, 0><<<dim3(1024 / 128, 4096 / 64), 256, 0, stream>>>(
        hcur, 512, nullptr, WgcBF, 1024, 512, XTABg, 1024,
        charseqs, charseq_lens, t, nullptr, nullptr, nullptr, Gc, 1024);
    cgemm_mfma<64, 1, 1><<<dim3(512 / 64, 4096 / 64), 256, 0, stream>>>(
        hcur, 512, Gc, WccBF, 512, 512, XTABc, 512,
        charseqs, charseq_lens, t, nullptr, nullptr, hcur, hnext, 512);
    float* tmp = hcur; hcur = hnext; hnext = tmp;
  }
  // after 16 steps hcur == HcA

  // --- Stage C: per-wordform x-part (bf16 MFMA, r24: AM=3/EM=3) ---
  {
    cgemm_mfma<128, 3, 3><<<dim3(1024 / 128, 2048 / 64), 256, 0, stream>>>(
        hcur, 512, nullptr, WgsBF, 1024, 1024, bg_w, 0,
        nullptr, nullptr, 0, nullptr, nullptr, nullptr, CTABg, 1024);
    cgemm_mfma<64, 3, 3><<<dim3(512 / 64, 2048 / 64), 256, 0, stream>>>(
        hcur, 512, nullptr, WcsBF, 512, 1024, bc_w, 0,
        nullptr, nullptr, 0, nullptr, nullptr, nullptr, CTABc, 512);
  }

  // --- Stage D: word-emb x-part + CTAB gather (bf16 MFMA) ---
  {
    cgemm_mfma<128, 2, 2><<<dim3(1024 / 128, 16384 / 64), 256, 0, stream>>>(
        word_emb, 256, nullptr, WgwBF, 1024, 256, CTABg, 1024,
        nullptr, nullptr, 0, word_ids, charseq_ids, nullptr, XWg, 1024);
    cgemm_mfma<64, 2, 2><<<dim3(512 / 64, 16384 / 64), 256, 0, stream>>>(
        word_emb, 256, nullptr, WcwBF, 512, 256, CTABc, 512,
        nullptr, nullptr, 0, word_ids, charseq_ids, nullptr, XWc, 512);
  }

  // --- Stage E: fused word bi-GRU, bf16 weights (R=2, 256 blocks x 256 thr) ---
  gru_word_bf<2, 256, 64><<<256, 256, 0, stream>>>(
      WhgBF, WhcBF, XWg, XWc, sentence_lens, Hw);

  // --- Stage F: FC head ---
  head_k<<<256, 64, 0, stream>>>(Hw, W1, b1, W2, b2, out);
}